// Round 1
// baseline (8294.534 us; speedup 1.0000x reference)
//
#include <hip/hip_runtime.h>

#define R 64
#define NX 16384
#define NV 2048
#define NXP (NX+8)
#define NVP (NV+8)
#define TW 64
#define SPLIT_VM 8
#define SPLIT_X 64
#define SPLIT_QRX 32
#define SPLIT_QRV 8

#define DXf 1.220703125e-4f
#define DVf 0.0078125f
#define DTf 0.001f
#define PI_F 3.14159265358979323846f
#define FAC_E (-1.0f)
#define FAC_I (0.01f)
#define ZE_F (-1.0f)
#define ZI_F (1.0f)
#define SQRT_DXf 0.011048543456039806f
#define SQRT_DVf 0.08838834764831845f
#define ISQRT_DXf 90.50966799187808f
#define ISQRT_DVf 11.313708498984761f

// ---------------- workspace layout (float offsets), per-species stride SPS ----
#define X_OFF 0
#define V_OFF 1048576
#define S_OFF 1179648
#define S1_OFF 1183744
#define SQ_OFF 1187840
#define D_OFF 1191936
#define MATS_OFF 1196032      /* 8 mats: vplus,vminus,Vm,Vp,Vl,Vr,Vmq,Vpq */
#define SM_OFF 1228800        /* KL,KR,EpM,EmM finals */
#define R1D_OFF 1245184       /* f64 64x64 */
#define RFD_OFF 1261568       /* f64 64x64 */
#define R1IF_OFF 1269760      /* f32 */
#define R2IF_OFF 1273856      /* f32 */
#define KA_OFF 1277952        /* 64 x NXP padded */
#define KB_OFF 2327040        /* 64 x NXP padded ; L-phase aliases below */
#define LA_OFF KB_OFF
#define LB_OFF (KB_OFF+131584)
#define Q1L_OFF (KB_OFF+263168)
#define VQ_OFF (KB_OFF+394240)
#define PART_OFF 3376128      /* f32 partials: 4 mats x 64 splits x 4096 */
#define PARTQR_OFF 4424704    /* f64 partials: 32 x 4096 doubles */
#define SPS 4686848
// shared region
#define RHO_OFF 9373696
#define E_OFF 9390080
#define C_OFF 9406464
#define FFT1_OFF 9410560
#define FFT2_OFF 9443328

__device__ __forceinline__ float mm2(float a, float b) {
    return (a*b > 0.0f) ? ((fabsf(a) < fabsf(b)) ? a : b) : 0.0f;
}

// ---------------- generic weighted gram: C[a][b] = sum_x av(a,x)*bv(b,x) ------
// mode 0: 6 V-matrices   mode 1: Vm/Vp masks from Vq   mode 2: K_left/K_right
// mode 3: Ep_mat/Em_mat (weight from fac*E, *DX)
__global__ __launch_bounds__(256) void k_gram(float* W, int mode, int a_off, int lda,
    int b_off, int ldb, int boff, int e_abs, float fac0, float fac1,
    int out_off, int N, int nsplit)
{
  int sp = blockIdx.z, mat = blockIdx.y, split = blockIdx.x;
  float* base = W + (size_t)sp*SPS;
  const float* A = base + a_off;
  const float* B = base + b_off;
  float fac = sp ? fac1 : fac0;
  float* outp = base + out_off + (size_t)(mat*nsplit + split)*4096;
  int chunk = N / nsplit;
  int xb0 = split * chunk;
  __shared__ float tA[TW][R+1], tB[TW][R+1];
  float acc[4][4] = {};
  int tid = threadIdx.x, ty = tid >> 4, tx = tid & 15;
  for (int xt = 0; xt < chunk; xt += TW) {
    for (int idx = tid; idx < TW*R; idx += 256) {
      int xi = idx & 63, r = idx >> 6;
      int x = xb0 + xt + xi;
      float av, bv;
      if (mode == 0) {
        float vv = A[(size_t)r*lda + x];
        float vs = ((float)x + 0.5f)*DVf - 8.0f;
        if (mat == 0)      { av = vv * (fmaxf(vs,0.f)*DVf); bv = vv; }
        else if (mat == 1) { av = vv * (fminf(vs,0.f)*DVf); bv = vv; }
        else if (mat == 2) { av = vv * ((vs<0.f)?DVf:0.f); bv = vv; }
        else if (mat == 3) { av = vv * ((vs>0.f)?DVf:0.f); bv = vv; }
        else if (mat == 4) { av = vv; bv = (x>=1)   ? (vv - A[(size_t)r*lda + x-1]) : 0.f; }
        else               { av = vv; bv = (x<NV-1) ? (A[(size_t)r*lda + x+1] - vv) : 0.f; }
      } else if (mode == 1) {
        float vv = A[(size_t)r*lda + x];
        float vs = ((float)x + 0.5f)*DVf - 8.0f;
        float w = (mat==0) ? ((vs<0.f)?DVf:0.f) : ((vs>0.f)?DVf:0.f);
        av = vv*w; bv = vv;
      } else if (mode == 2) {
        av = A[(size_t)r*lda + x];
        const float* Bp = B + (size_t)r*ldb + boff + x;
        bv = (mat==0) ? (Bp[0] - Bp[-1]) : (Bp[1] - Bp[0]);
      } else {
        float e = W[e_abs + x] * fac;
        float vv = A[(size_t)r*lda + x];
        av = vv * (((mat==0) ? fmaxf(e,0.f) : fminf(e,0.f)) * DXf);
        bv = vv;
      }
      tA[xi][r] = av; tB[xi][r] = bv;
    }
    __syncthreads();
    for (int xi = 0; xi < TW; ++xi) {
      float a0 = tA[xi][ty*4+0], a1 = tA[xi][ty*4+1], a2 = tA[xi][ty*4+2], a3 = tA[xi][ty*4+3];
      float b0 = tB[xi][tx*4+0], b1 = tB[xi][tx*4+1], b2 = tB[xi][tx*4+2], b3 = tB[xi][tx*4+3];
      acc[0][0]+=a0*b0; acc[0][1]+=a0*b1; acc[0][2]+=a0*b2; acc[0][3]+=a0*b3;
      acc[1][0]+=a1*b0; acc[1][1]+=a1*b1; acc[1][2]+=a1*b2; acc[1][3]+=a1*b3;
      acc[2][0]+=a2*b0; acc[2][1]+=a2*b1; acc[2][2]+=a2*b2; acc[2][3]+=a2*b3;
      acc[3][0]+=a3*b0; acc[3][1]+=a3*b1; acc[3][2]+=a3*b2; acc[3][3]+=a3*b3;
    }
    __syncthreads();
  }
  #pragma unroll
  for (int i = 0; i < 4; ++i)
    #pragma unroll
    for (int j = 0; j < 4; ++j)
      outp[(ty*4+i)*64 + tx*4 + j] = acc[i][j];
}

// gram with fp64 accumulation for QR (A only)
__global__ __launch_bounds__(256) void k_gram_qr(float* W, int a_off, int lda, int aoff,
    int N, int nsplit, int outd_off)
{
  int sp = blockIdx.z, split = blockIdx.x;
  float* base = W + (size_t)sp*SPS;
  const float* A = base + a_off + aoff;
  double* outp = (double*)(base + outd_off) + (size_t)split*4096;
  int chunk = N / nsplit, x0 = split*chunk;
  __shared__ float tA[TW][R+1];
  double acc[4][4] = {};
  int tid = threadIdx.x, ty = tid >> 4, tx = tid & 15;
  for (int xt = 0; xt < chunk; xt += TW) {
    for (int idx = tid; idx < TW*R; idx += 256) {
      int xi = idx & 63, r = idx >> 6;
      tA[xi][r] = A[(size_t)r*lda + x0 + xt + xi];
    }
    __syncthreads();
    for (int xi = 0; xi < TW; ++xi) {
      double a0 = tA[xi][ty*4+0], a1 = tA[xi][ty*4+1], a2 = tA[xi][ty*4+2], a3 = tA[xi][ty*4+3];
      double b0 = tA[xi][tx*4+0], b1 = tA[xi][tx*4+1], b2 = tA[xi][tx*4+2], b3 = tA[xi][tx*4+3];
      acc[0][0]+=a0*b0; acc[0][1]+=a0*b1; acc[0][2]+=a0*b2; acc[0][3]+=a0*b3;
      acc[1][0]+=a1*b0; acc[1][1]+=a1*b1; acc[1][2]+=a1*b2; acc[1][3]+=a1*b3;
      acc[2][0]+=a2*b0; acc[2][1]+=a2*b1; acc[2][2]+=a2*b2; acc[2][3]+=a2*b3;
      acc[3][0]+=a3*b0; acc[3][1]+=a3*b1; acc[3][2]+=a3*b2; acc[3][3]+=a3*b3;
    }
    __syncthreads();
  }
  #pragma unroll
  for (int i = 0; i < 4; ++i)
    #pragma unroll
    for (int j = 0; j < 4; ++j)
      outp[(ty*4+i)*64 + tx*4 + j] = acc[i][j];
}

// reduce partial mats
__global__ __launch_bounds__(256) void k_reduce(float* W, int src_off, int dst_off, int nsplit)
{
  int sp = blockIdx.z, mat = blockIdx.x;
  float* base = W + (size_t)sp*SPS;
  const float* src = base + src_off + (size_t)mat*nsplit*4096;
  float* dst = base + dst_off + (size_t)mat*4096;
  for (int e = threadIdx.x; e < 4096; e += 256) {
    float s = 0;
    for (int k = 0; k < nsplit; ++k) s += src[(size_t)k*4096 + e];
    dst[e] = s;
  }
}

// C[j][x] = alpha*d[j]* sum_r coef(r,j) * B[r][x];  coef = transA? A[j][r] : A[r][j]
__global__ __launch_bounds__(256) void k_rr(float* W, int a_off, int transA, int b_off,
    int ldb, int boff, int c_off, int ldc, int coff, int d_off, float alpha)
{
  int sp = blockIdx.z;
  float* base = W + (size_t)sp*SPS;
  const float* A = base + a_off;
  const float* B = base + b_off + boff;
  float* C = base + c_off + coff;
  __shared__ float tA[R][R+1];
  __shared__ float dsc[R];
  int tid = threadIdx.x;
  for (int idx = tid; idx < R*R; idx += 256) {
    int r = idx >> 6, j = idx & 63;
    tA[r][j] = transA ? A[j*R + r] : A[idx];
  }
  if (tid < R) dsc[tid] = (d_off >= 0) ? base[d_off + tid] : 1.0f;
  __syncthreads();
  int ty = tid >> 4, tx = tid & 15;
  int x0 = blockIdx.x*64 + tx*4;
  float acc[4][4] = {};
  for (int r = 0; r < R; ++r) {
    float4 bv = *(const float4*)(B + (size_t)r*ldb + x0);
    float a0 = tA[r][ty*4+0], a1 = tA[r][ty*4+1], a2 = tA[r][ty*4+2], a3 = tA[r][ty*4+3];
    acc[0][0]+=a0*bv.x; acc[0][1]+=a0*bv.y; acc[0][2]+=a0*bv.z; acc[0][3]+=a0*bv.w;
    acc[1][0]+=a1*bv.x; acc[1][1]+=a1*bv.y; acc[1][2]+=a1*bv.z; acc[1][3]+=a1*bv.w;
    acc[2][0]+=a2*bv.x; acc[2][1]+=a2*bv.y; acc[2][2]+=a2*bv.z; acc[2][3]+=a2*bv.w;
    acc[3][0]+=a3*bv.x; acc[3][1]+=a3*bv.y; acc[3][2]+=a3*bv.z; acc[3][3]+=a3*bv.w;
  }
  #pragma unroll
  for (int i = 0; i < 4; ++i) {
    int j = ty*4 + i;
    float s = alpha * dsc[j];
    float4 o = make_float4(acc[i][0]*s, acc[i][1]*s, acc[i][2]*s, acc[i][3]*s);
    *(float4*)(C + (size_t)j*ldc + x0) = o;
  }
}

// ghosts for 2-ghost K buffer: cols 2,3 = Vm@K[:,{1,0}]; NX+4,NX+5 = Vp@K[:,{NX-1,NX-2}]
__global__ __launch_bounds__(256) void k_ghost2(float* W, int k_off)
{
  int sp = blockIdx.z;
  float* base = W + (size_t)sp*SPS;
  float* K = base + k_off;
  int tid = threadIdx.x;
  int j = tid & 63, c = tid >> 6;
  const float* M = base + MATS_OFF + ((c < 2) ? 2 : 3)*4096;
  int dst = (c==0)?2 : (c==1)?3 : (c==2)?(NX+4):(NX+5);
  int src = (c==0)?5 : (c==1)?4 : (c==2)?(NX+3):(NX+2);
  float s = 0;
  for (int m = 0; m < R; ++m) s += M[j*R + m] * K[(size_t)m*NXP + src];
  K[(size_t)j*NXP + dst] = s;
}

// ghosts for 1-ghost K buffer: col 3 = Vm@K[:,0]; NX+4 = Vp@K[:,NX-1]
__global__ __launch_bounds__(128) void k_ghost1(float* W, int k_off, int vm_idx, int vp_idx)
{
  int sp = blockIdx.z;
  float* base = W + (size_t)sp*SPS;
  float* K = base + k_off;
  int tid = threadIdx.x;
  int j = tid & 63, c = tid >> 6;
  const float* M = base + MATS_OFF + ((c==0)? vm_idx : vp_idx)*4096;
  int dst = (c==0)? 3 : (NX+4);
  int src = (c==0)? 4 : (NX+3);
  float s = 0;
  for (int m = 0; m < R; ++m) s += M[j*R + m] * K[(size_t)m*NXP + src];
  K[(size_t)j*NXP + dst] = s;
}

__global__ __launch_bounds__(256) void k_ghostL(float* W)
{
  int sp = blockIdx.z;
  float* base = W + (size_t)sp*SPS;
  for (int idx = threadIdx.x; idx < 512; idx += 256) {
    int which = idx >> 8; int r = (idx >> 2) & 63; int c = idx & 3;
    int col = (c < 2) ? (2 + c) : (NV + 4 + (c - 2));
    (base + (which ? LB_OFF : LA_OFF))[(size_t)r*NVP + col] = 0.f;
  }
}

// fused slope-limited flux divergence + extra term + SSPRK2 combine
__global__ __launch_bounds__(256) void k_flux(float* W, int U_off, int Kx_off, int ldkx,
    int kxoff, int useWin, int P_off, int Mi_off, int A2_off, int B2_off,
    int e_abs, float fac0, float fac1, float dh_inv, int N, int ldp,
    int stage, int orig_off, int out_off)
{
  int sp = blockIdx.z;
  float* base = W + (size_t)sp*SPS;
  const float* U  = base + U_off;
  const float* Kx = base + Kx_off;
  const float* Pm = base + P_off;
  const float* Mm = base + Mi_off;
  const float* Am = base + A2_off;
  const float* Bm = base + B2_off;
  float fac = sp ? fac1 : fac0;
  int x0 = blockIdx.x * 32;
  __shared__ float win[R][37];
  __shared__ float dLt[32][R+1];
  __shared__ float dRt[32][R+1];
  __shared__ float KTt[32][R+1];
  int tid = threadIdx.x;
  for (int idx = tid; idx < R*36; idx += 256) {
    int c = idx % 36, m = idx / 36;
    win[m][c] = U[(size_t)m*ldp + x0 + 2 + c];
  }
  __syncthreads();
  for (int idx = tid; idx < R*32; idx += 256) {
    int xi = idx & 31, m = idx >> 5;
    float u0 = win[m][xi], u1 = win[m][xi+1], u2 = win[m][xi+2], u3 = win[m][xi+3], u4 = win[m][xi+4];
    float d01 = u1-u0, d12 = u2-u1, d23 = u3-u2, d34 = u4-u3;
    float s1 = mm2(d01,d12), s2 = mm2(d12,d23), s3 = mm2(d23,d34);
    dLt[xi][m] = ((u2 + 0.5f*s2) - (u1 + 0.5f*s1)) * dh_inv;
    dRt[xi][m] = ((u3 - 0.5f*s3) - (u2 - 0.5f*s2)) * dh_inv;
    KTt[xi][m] = useWin ? u2 : Kx[(size_t)m*ldkx + kxoff + x0 + xi];
  }
  __syncthreads();
  int ty = tid >> 4, tx = tid & 15;
  int j0 = ty*4;
  float aP[4][2] = {}, aM[4][2] = {}, aA[4][2] = {}, aB[4][2] = {};
  for (int m = 0; m < R; ++m) {
    float dl0 = dLt[tx*2][m],   dl1 = dLt[tx*2+1][m];
    float dr0 = dRt[tx*2][m],   dr1 = dRt[tx*2+1][m];
    float kt0 = KTt[tx*2][m],   kt1 = KTt[tx*2+1][m];
    #pragma unroll
    for (int i = 0; i < 4; ++i) {
      float p = Pm[(j0+i)*R + m], q = Mm[(j0+i)*R + m];
      float a = Am[(j0+i)*R + m], b = Bm[(j0+i)*R + m];
      aP[i][0] += p*dl0; aP[i][1] += p*dl1;
      aM[i][0] += q*dr0; aM[i][1] += q*dr1;
      aA[i][0] += a*kt0; aA[i][1] += a*kt1;
      aB[i][0] += b*kt0; aB[i][1] += b*kt1;
    }
  }
  const float* orig = base + orig_off;
  float* out = base + out_off;
  for (int xx = 0; xx < 2; ++xx) {
    int x = x0 + tx*2 + xx;
    float w1, w2;
    if (e_abs >= 0) { float e = W[e_abs + x]; w1 = fac*fmaxf(e,0.f); w2 = fac*fminf(e,0.f); }
    else { float vs = ((float)x + 0.5f)*DVf - 8.0f; w1 = fmaxf(vs,0.f); w2 = fminf(vs,0.f); }
    #pragma unroll
    for (int i = 0; i < 4; ++i) {
      int j = j0 + i;
      float rhs = -(aP[i][xx] + aM[i][xx] + w1*aA[i][xx] + w2*aB[i][xx]);
      float uval = win[j][tx*2 + xx + 2];
      float res;
      if (stage == 1) res = uval + DTf*rhs;
      else res = 0.5f*(orig[(size_t)j*ldp + 4 + x] + uval + DTf*rhs);
      out[(size_t)j*ldp + 4 + x] = res;
    }
  }
}

// reduce fp64 gram partials + Cholesky + triangular inverse -> R1(f64), R1inv(f32)
__global__ __launch_bounds__(64) void k_chol1(float* W, int partd_off, int nsplit)
{
  int sp = blockIdx.z;
  float* base = W + (size_t)sp*SPS;
  const double* P = (const double*)(base + partd_off);
  double* R1 = (double*)(base + R1D_OFF);
  float* R1i = base + R1IF_OFF;
  __shared__ double G[R][R+1];
  int tid = threadIdx.x;
  for (int e = tid; e < 4096; e += 64) {
    double s = 0;
    for (int k = 0; k < nsplit; ++k) s += P[(size_t)k*4096 + e];
    G[e>>6][e&63] = s;
  }
  __syncthreads();
  for (int k = 0; k < R; ++k) {
    double ukk = sqrt(G[k][k]);
    if (tid == k) G[k][k] = ukk;
    else if (tid > k) G[k][tid] /= ukk;
    __syncthreads();
    if (tid > k) { double ukj = G[k][tid]; for (int i = k+1; i <= tid; ++i) G[i][tid] -= G[k][i]*ukj; }
    __syncthreads();
  }
  for (int e = tid; e < 4096; e += 64) { int i = e>>6, j = e&63; R1[e] = (i<=j) ? G[i][j] : 0.0; }
  {
    double w[R];
    int j = tid;
    w[j] = 1.0 / G[j][j];
    for (int i = j-1; i >= 0; --i) {
      double s = 0; for (int m = i+1; m <= j; ++m) s += G[i][m]*w[m];
      w[i] = -s / G[i][i];
    }
    for (int r = 0; r < R; ++r) R1i[r*R + j] = (r <= j) ? (float)w[r] : 0.0f;
  }
}

// reduce G2 + chol -> R2; R2inv(f32); Rf=R2@R1; top-block T; LAPACK sign recursion; S_out
__global__ __launch_bounds__(64) void k_chol2(float* W, int partd_off, int nsplit,
    int q1_off, int ldq, int qoff, int sout_off, float sscale)
{
  int sp = blockIdx.z;
  float* base = W + (size_t)sp*SPS;
  const double* P = (const double*)(base + partd_off);
  const double* R1 = (const double*)(base + R1D_OFF);
  double* RF = (double*)(base + RFD_OFF);
  float* R2i = base + R2IF_OFF;
  __shared__ double G[R][R+1];
  __shared__ double dsh[R];
  int tid = threadIdx.x;
  for (int e = tid; e < 4096; e += 64) {
    double s = 0;
    for (int k = 0; k < nsplit; ++k) s += P[(size_t)k*4096 + e];
    G[e>>6][e&63] = s;
  }
  __syncthreads();
  for (int k = 0; k < R; ++k) {
    double ukk = sqrt(G[k][k]);
    if (tid == k) G[k][k] = ukk;
    else if (tid > k) G[k][tid] /= ukk;
    __syncthreads();
    if (tid > k) { double ukj = G[k][tid]; for (int i = k+1; i <= tid; ++i) G[i][tid] -= G[k][i]*ukj; }
    __syncthreads();
  }
  // Rf column tid = R2 @ R1
  for (int i = 0; i < R; ++i) {
    double s = 0;
    if (i <= tid) for (int m = i; m <= tid; ++m) s += G[i][m] * R1[m*R + tid];
    RF[i*R + tid] = s;
  }
  // back-substitution: column tid of R2inv
  double w[R];
  {
    int j = tid;
    w[j] = 1.0 / G[j][j];
    for (int i = j-1; i >= 0; --i) {
      double s = 0; for (int m = i+1; m <= j; ++m) s += G[i][m]*w[m];
      w[i] = -s / G[i][i];
    }
    for (int r = 0; r < R; ++r) R2i[r*R + j] = (r <= j) ? (float)w[r] : 0.0f;
  }
  __syncthreads();
  // T[x][tid] = (Q1 @ R2inv)[x][tid], x<64  (top block of Q_pos), overwrite G
  const float* Q1 = base + q1_off + qoff;
  for (int x = 0; x < R; ++x) {
    double s = 0;
    for (int m = 0; m <= tid; ++m) s += w[m] * (double)Q1[(size_t)m*ldq + x];
    G[x][tid] = s;
  }
  __syncthreads();
  // LAPACK Householder sign chain on exact-orthonormal top block
  for (int k = 0; k < R; ++k) {
    double tkk = G[k][k];
    double d = (tkk >= 0.0) ? -1.0 : 1.0;
    if (tid == k) dsh[k] = d;
    if (tid > k) {
      double c = d * G[k][tid] / (1.0 + fabs(tkk));
      for (int m = k+1; m < R; ++m) G[m][tid] += c * G[m][k];
    }
    __syncthreads();
  }
  base[D_OFF + tid] = (float)dsh[tid];
  for (int e = tid; e < 4096; e += 64) {
    int i = e >> 6;
    base[sout_off + e] = (float)(dsh[i] * RF[e] * (double)sscale);
  }
}

// S-step small combine: reduce partials, rhs = KL@vp^T + KR@vm^T + fac*(Ep@S@Vl^T + Em@S@Vr^T)
__global__ __launch_bounds__(256) void k_sstep(float* W, int stage)
{
  int sp = blockIdx.x;
  float* base = W + (size_t)sp*SPS;
  const float* part = base + PART_OFF;
  float fac = sp ? FAC_I : FAC_E;
  __shared__ float Ab[4096], Bb[4096], Cb[4096];
  int tid = threadIdx.x, ty = tid >> 4, tx = tid & 15;
  for (int e = tid; e < 4096; e += 256) {
    float s0 = 0, s1 = 0;
    for (int k = 0; k < SPLIT_X; ++k) {
      s0 += part[(size_t)(0*SPLIT_X+k)*4096 + e];
      s1 += part[(size_t)(1*SPLIT_X+k)*4096 + e];
    }
    Ab[e] = s0; Bb[e] = s1;
  }
  __syncthreads();
  const float* vpm = base + MATS_OFF + 0*4096;
  const float* vmm = base + MATS_OFF + 1*4096;
  const float* vlm = base + MATS_OFF + 4*4096;
  const float* vrm = base + MATS_OFF + 5*4096;
  float accV[4][4] = {}, accE[4][4] = {};
  for (int m = 0; m < R; ++m) {
    float kl[4], kr[4], vpj[4], vmj[4];
    #pragma unroll
    for (int i = 0; i < 4; ++i) { kl[i] = Ab[(ty*4+i)*64+m]; kr[i] = Bb[(ty*4+i)*64+m]; }
    #pragma unroll
    for (int j = 0; j < 4; ++j) { vpj[j] = vpm[(tx*4+j)*64+m]; vmj[j] = vmm[(tx*4+j)*64+m]; }
    #pragma unroll
    for (int i = 0; i < 4; ++i)
      #pragma unroll
      for (int j = 0; j < 4; ++j)
        accV[i][j] += kl[i]*vpj[j] + kr[i]*vmj[j];
  }
  __syncthreads();
  const float* Sin = base + ((stage==1)? S_OFF : S1_OFF);
  for (int e = tid; e < 4096; e += 256) Cb[e] = Sin[e];
  for (int e = tid; e < 4096; e += 256) {
    float s = 0;
    for (int k = 0; k < SPLIT_X; ++k) s += part[(size_t)(2*SPLIT_X+k)*4096 + e];
    Ab[e] = s;
  }
  __syncthreads();
  float t1[4][4] = {};
  for (int m = 0; m < R; ++m) {
    float ar[4], cj[4];
    #pragma unroll
    for (int i = 0; i < 4; ++i) ar[i] = Ab[(ty*4+i)*64+m];
    #pragma unroll
    for (int j = 0; j < 4; ++j) cj[j] = Cb[m*64 + tx*4+j];
    #pragma unroll
    for (int i = 0; i < 4; ++i)
      #pragma unroll
      for (int j = 0; j < 4; ++j) t1[i][j] += ar[i]*cj[j];
  }
  __syncthreads();
  #pragma unroll
  for (int i = 0; i < 4; ++i)
    #pragma unroll
    for (int j = 0; j < 4; ++j) Bb[(ty*4+i)*64 + tx*4+j] = t1[i][j];
  __syncthreads();
  for (int m = 0; m < R; ++m) {
    float ar[4], vj[4];
    #pragma unroll
    for (int i = 0; i < 4; ++i) ar[i] = Bb[(ty*4+i)*64+m];
    #pragma unroll
    for (int j = 0; j < 4; ++j) vj[j] = vlm[(tx*4+j)*64+m];
    #pragma unroll
    for (int i = 0; i < 4; ++i)
      #pragma unroll
      for (int j = 0; j < 4; ++j) accE[i][j] += ar[i]*vj[j];
  }
  __syncthreads();
  for (int e = tid; e < 4096; e += 256) {
    float s = 0;
    for (int k = 0; k < SPLIT_X; ++k) s += part[(size_t)(3*SPLIT_X+k)*4096 + e];
    Ab[e] = s;
  }
  __syncthreads();
  float t2[4][4] = {};
  for (int m = 0; m < R; ++m) {
    float ar[4], cj[4];
    #pragma unroll
    for (int i = 0; i < 4; ++i) ar[i] = Ab[(ty*4+i)*64+m];
    #pragma unroll
    for (int j = 0; j < 4; ++j) cj[j] = Cb[m*64 + tx*4+j];
    #pragma unroll
    for (int i = 0; i < 4; ++i)
      #pragma unroll
      for (int j = 0; j < 4; ++j) t2[i][j] += ar[i]*cj[j];
  }
  __syncthreads();
  #pragma unroll
  for (int i = 0; i < 4; ++i)
    #pragma unroll
    for (int j = 0; j < 4; ++j) Bb[(ty*4+i)*64 + tx*4+j] = t2[i][j];
  __syncthreads();
  for (int m = 0; m < R; ++m) {
    float ar[4], vj[4];
    #pragma unroll
    for (int i = 0; i < 4; ++i) ar[i] = Bb[(ty*4+i)*64+m];
    #pragma unroll
    for (int j = 0; j < 4; ++j) vj[j] = vrm[(tx*4+j)*64+m];
    #pragma unroll
    for (int i = 0; i < 4; ++i)
      #pragma unroll
      for (int j = 0; j < 4; ++j) accE[i][j] += ar[i]*vj[j];
  }
  #pragma unroll
  for (int i = 0; i < 4; ++i)
    #pragma unroll
    for (int j = 0; j < 4; ++j) {
      int e = (ty*4+i)*64 + tx*4+j;
      float rhs = accV[i][j] + fac*accE[i][j];
      if (stage == 1) base[S1_OFF + e] = base[S_OFF + e] + DTf*rhs;
      else base[S_OFF + e] = 0.5f*(base[S_OFF + e] + base[S1_OFF + e] + DTf*rhs);
    }
}

// charge moments: c = Z * S @ (V @ 1 * DV)
__global__ __launch_bounds__(256) void k_csolve(float* W)
{
  int sp = blockIdx.x;
  float* base = W + (size_t)sp*SPS;
  const float* V = base + V_OFF;
  const float* S = base + S_OFF;
  __shared__ float red[R][4];
  __shared__ float mass[R];
  int tid = threadIdx.x;
  int r = tid >> 2, q = tid & 3;
  float s = 0;
  for (int v = q; v < NV; v += 4) s += V[(size_t)r*NV + v];
  red[r][q] = s;
  __syncthreads();
  if (tid < R) mass[tid] = (red[tid][0]+red[tid][1]+red[tid][2]+red[tid][3]) * DVf;
  __syncthreads();
  if (tid < R) {
    float c = 0;
    for (int j = 0; j < R; ++j) c += S[tid*R + j] * mass[j];
    W[C_OFF + sp*R + tid] = c * (sp ? ZI_F : ZE_F);
  }
}

__global__ __launch_bounds__(256) void k_rho(float* W)
{
  int x = blockIdx.x*256 + threadIdx.x;
  float s = 0;
  for (int r = 0; r < R; ++r) s += W[X_OFF + (size_t)r*NX + x] * W[C_OFF + r];
  for (int r = 0; r < R; ++r) s += W[(size_t)SPS + X_OFF + (size_t)r*NX + x] * W[C_OFF + R + r];
  W[RHO_OFF + x] = s;
}

// -------- FFT: length-128 radix-2 DIT in LDS, 64 threads --------
__device__ inline void fft128fwd(float2* b, int t)
{
  __syncthreads();
  int r0 = (int)(__brev((unsigned)t) >> 25);
  int r1 = (int)(__brev((unsigned)(t+64)) >> 25);
  float2 a0 = b[r0], a1 = b[r1];
  __syncthreads();
  b[t] = a0; b[t+64] = a1;
  for (int s = 1; s <= 7; ++s) {
    __syncthreads();
    int half = 1 << (s-1);
    int jj = t & (half-1);
    int g  = t >> (s-1);
    int pos = (g << s) + jj;
    float ang = -2.0f*PI_F*(float)jj / (float)(1 << s);
    float sn, cs; sincosf(ang, &sn, &cs);
    float2 u = b[pos], wv = b[pos+half];
    float2 v = make_float2(wv.x*cs - wv.y*sn, wv.x*sn + wv.y*cs);
    b[pos] = make_float2(u.x+v.x, u.y+v.y);
    b[pos+half] = make_float2(u.x-v.x, u.y-v.y);
  }
}

// pass A: per-n1 length-128 FFT over n2 (stride 128) + four-step twiddle, write transposed
__global__ __launch_bounds__(64) void k_fftA(float* W, int rin_off, int cin_off, int out_off)
{
  __shared__ float2 bb[128];
  int n1 = blockIdx.x, t = threadIdx.x;
  if (rin_off >= 0) {
    const float* rin = W + rin_off;
    bb[t]    = make_float2(rin[n1 + 128*t], 0.f);
    bb[t+64] = make_float2(rin[n1 + 128*(t+64)], 0.f);
  } else {
    const float2* cin = (const float2*)(W + cin_off);
    bb[t] = cin[n1 + 128*t]; bb[t+64] = cin[n1 + 128*(t+64)];
  }
  fft128fwd(bb, t);
  __syncthreads();
  float2* outp = (float2*)(W + out_off);
  for (int kk = 0; kk < 2; ++kk) {
    int k2 = t + 64*kk;
    float ang = -2.0f*PI_F*(float)(n1*k2) * (1.0f/16384.0f);
    float sn, cs; sincosf(ang, &sn, &cs);
    float2 v = bb[k2];
    outp[k2*128 + n1] = make_float2(v.x*cs - v.y*sn, v.x*sn + v.y*cs);
  }
}

// pass B: per-k2 FFT over n1; spectral scale 1/(ik); write conj(H) in natural order
__global__ __launch_bounds__(64) void k_fftB(float* W, int in_off, int out_off)
{
  __shared__ float2 bb[128];
  int k2 = blockIdx.x, t = threadIdx.x;
  const float2* in = (const float2*)(W + in_off);
  bb[t] = in[k2*128 + t]; bb[t+64] = in[k2*128 + t + 64];
  fft128fwd(bb, t);
  __syncthreads();
  float2* outp = (float2*)(W + out_off);
  for (int kk = 0; kk < 2; ++kk) {
    int k1 = t + 64*kk;
    int j = k2 + 128*k1;
    float2 X = bb[k1];
    float2 Hc;
    if (j == 0) Hc = make_float2(0.f, 0.f);
    else {
      float kphys = PI_F * (float)((j < 8192) ? j : (j - 16384));
      Hc = make_float2(X.y / kphys, X.x / kphys);   // conj(rho_hat/(i k))
    }
    outp[j] = Hc;
  }
}

// pass D: final FFT pass, take Re()/N -> E
__global__ __launch_bounds__(64) void k_fftD(float* W, int in_off, int e_off)
{
  __shared__ float2 bb[128];
  int k2 = blockIdx.x, t = threadIdx.x;
  const float2* in = (const float2*)(W + in_off);
  bb[t] = in[k2*128 + t]; bb[t+64] = in[k2*128 + t + 64];
  fft128fwd(bb, t);
  __syncthreads();
  for (int kk = 0; kk < 2; ++kk) {
    int k1 = t + 64*kk;
    W[e_off + k2 + 128*k1] = bb[k1].x * (1.0f/16384.0f);
  }
}

// ----------------------------------------------------------------------------
extern "C" void kernel_launch(void* const* d_in, const int* in_sizes, int n_in,
                              void* d_out, int out_size, void* d_ws, size_t ws_size,
                              hipStream_t stream)
{
  float* W = (float*)d_ws;
  const size_t FB = sizeof(float);
  // inputs: Xe, Se, Ve, Xi, Si, Vi
  hipMemcpyAsync(W + X_OFF, d_in[0], FB*(size_t)R*NX, hipMemcpyDeviceToDevice, stream);
  hipMemcpyAsync(W + S_OFF, d_in[1], FB*(size_t)R*R,  hipMemcpyDeviceToDevice, stream);
  hipMemcpyAsync(W + V_OFF, d_in[2], FB*(size_t)R*NV, hipMemcpyDeviceToDevice, stream);
  hipMemcpyAsync(W + (size_t)SPS + X_OFF, d_in[3], FB*(size_t)R*NX, hipMemcpyDeviceToDevice, stream);
  hipMemcpyAsync(W + (size_t)SPS + S_OFF, d_in[4], FB*(size_t)R*R,  hipMemcpyDeviceToDevice, stream);
  hipMemcpyAsync(W + (size_t)SPS + V_OFF, d_in[5], FB*(size_t)R*NV, hipMemcpyDeviceToDevice, stream);

  // V-derived matrices (vplus,vminus,Vm,Vp,Vl,Vr)
  k_gram<<<dim3(SPLIT_VM,6,2),256,0,stream>>>(W, 0, V_OFF, NV, V_OFF, NV, 0, -1, 0.f,0.f, PART_OFF, NV, SPLIT_VM);
  k_reduce<<<dim3(6,1,2),256,0,stream>>>(W, PART_OFF, MATS_OFF, SPLIT_VM);

  auto poisson = [&]() {
    k_csolve<<<dim3(2),256,0,stream>>>(W);
    k_rho<<<dim3(NX/256),256,0,stream>>>(W);
    k_fftA<<<dim3(128),64,0,stream>>>(W, RHO_OFF, -1, FFT1_OFF);
    k_fftB<<<dim3(128),64,0,stream>>>(W, FFT1_OFF, FFT2_OFF);
    k_fftA<<<dim3(128),64,0,stream>>>(W, -1, FFT2_OFF, FFT1_OFF);
    k_fftD<<<dim3(128),64,0,stream>>>(W, FFT1_OFF, E_OFF);
  };

  auto qr = [&](int a_off, int lda, int aoff, int N_, int nsplit,
                int q1_off, int q1_ld, int q1_aoff,
                int sout_off, float sscale, int xout_off, int xout_ld, float inv_s) {
    k_gram_qr<<<dim3(nsplit,1,2),256,0,stream>>>(W, a_off, lda, aoff, N_, nsplit, PARTQR_OFF);
    k_chol1<<<dim3(1,1,2),64,0,stream>>>(W, PARTQR_OFF, nsplit);
    k_rr<<<dim3(N_/64,1,2),256,0,stream>>>(W, R1IF_OFF, 0, a_off, lda, aoff, q1_off, q1_ld, q1_aoff, -1, 1.0f);
    k_gram_qr<<<dim3(nsplit,1,2),256,0,stream>>>(W, q1_off, q1_ld, q1_aoff, N_, nsplit, PARTQR_OFF);
    k_chol2<<<dim3(1,1,2),64,0,stream>>>(W, PARTQR_OFF, nsplit, q1_off, q1_ld, q1_aoff, sout_off, sscale);
    k_rr<<<dim3(N_/64,1,2),256,0,stream>>>(W, R2IF_OFF, 0, q1_off, q1_ld, q1_aoff, xout_off, xout_ld, 0, D_OFF, inv_s);
  };

  // ---------- Poisson #1 + K-step ----------
  poisson();
  k_rr<<<dim3(NX/64,1,2),256,0,stream>>>(W, S_OFF, 0, X_OFF, NX, 0, KA_OFF, NXP, 4, -1, 1.0f);
  k_ghost2<<<dim3(1,1,2),256,0,stream>>>(W, KA_OFF);
  k_flux<<<dim3(NX/32,1,2),256,0,stream>>>(W, KA_OFF, KA_OFF, NXP, 4, 1,
      MATS_OFF+0*4096, MATS_OFF+1*4096, MATS_OFF+4*4096, MATS_OFF+5*4096,
      E_OFF, FAC_E, FAC_I, 1.0f/DXf, NX, NXP, 1, 0, KB_OFF);
  k_ghost2<<<dim3(1,1,2),256,0,stream>>>(W, KB_OFF);
  k_flux<<<dim3(NX/32,1,2),256,0,stream>>>(W, KB_OFF, KB_OFF, NXP, 4, 1,
      MATS_OFF+0*4096, MATS_OFF+1*4096, MATS_OFF+4*4096, MATS_OFF+5*4096,
      E_OFF, FAC_E, FAC_I, 1.0f/DXf, NX, NXP, 2, KA_OFF, KA_OFF);
  qr(KA_OFF, NXP, 4, NX, SPLIT_QRX, KB_OFF, NXP, 4, S_OFF, SQRT_DXf, X_OFF, NX, ISQRT_DXf);

  // ---------- Poisson #2 + S-step ----------
  poisson();
  auto sstep_eval = [&](int stage) {
    int sin = (stage==1) ? S_OFF : S1_OFF;
    k_rr<<<dim3(NX/64,1,2),256,0,stream>>>(W, sin, 0, X_OFF, NX, 0, KA_OFF, NXP, 4, -1, 1.0f);
    k_ghost1<<<dim3(1,1,2),128,0,stream>>>(W, KA_OFF, 2, 3);
    k_gram<<<dim3(SPLIT_X,2,2),256,0,stream>>>(W, 2, X_OFF, NX, KA_OFF, NXP, 4, -1, 0.f,0.f, PART_OFF, NX, SPLIT_X);
    k_gram<<<dim3(SPLIT_X,2,2),256,0,stream>>>(W, 3, X_OFF, NX, 0, 0, 0, E_OFF, 1.0f, 1.0f, PART_OFF + 2*SPLIT_X*4096, NX, SPLIT_X);
    k_sstep<<<dim3(2),256,0,stream>>>(W, stage);
  };
  sstep_eval(1);
  sstep_eval(2);

  // ---------- Poisson #3 + L-step ----------
  poisson();
  k_rr<<<dim3(NV/64,1,2),256,0,stream>>>(W, S_OFF, 1, V_OFF, NV, 0, LA_OFF, NVP, 4, -1, 1.0f);
  k_ghostL<<<dim3(1,1,2),256,0,stream>>>(W);
  auto leval = [&](int Lsrc, int stage, int Ldst, int Lorig) {
    qr(Lsrc, NVP, 4, NV, SPLIT_QRV, Q1L_OFF, NV, 0, SQ_OFF, SQRT_DVf, VQ_OFF, NV, ISQRT_DVf);
    k_gram<<<dim3(SPLIT_VM,2,2),256,0,stream>>>(W, 1, VQ_OFF, NV, VQ_OFF, NV, 0, -1, 0.f,0.f, PART_OFF, NV, SPLIT_VM);
    k_reduce<<<dim3(2,1,2),256,0,stream>>>(W, PART_OFF, MATS_OFF + 6*4096, SPLIT_VM);
    k_rr<<<dim3(NX/64,1,2),256,0,stream>>>(W, SQ_OFF, 0, X_OFF, NX, 0, KA_OFF, NXP, 4, -1, 1.0f);
    k_ghost1<<<dim3(1,1,2),128,0,stream>>>(W, KA_OFF, 6, 7);
    k_gram<<<dim3(SPLIT_X,2,2),256,0,stream>>>(W, 2, X_OFF, NX, KA_OFF, NXP, 4, -1, 0.f,0.f, PART_OFF, NX, SPLIT_X);
    k_gram<<<dim3(SPLIT_X,2,2),256,0,stream>>>(W, 3, X_OFF, NX, 0, 0, 0, E_OFF, FAC_E, FAC_I, PART_OFF + 2*SPLIT_X*4096, NX, SPLIT_X);
    k_reduce<<<dim3(4,1,2),256,0,stream>>>(W, PART_OFF, SM_OFF, SPLIT_X);
    k_flux<<<dim3(NV/32,1,2),256,0,stream>>>(W, Lsrc, VQ_OFF, NV, 0, 0,
        SM_OFF+2*4096, SM_OFF+3*4096, SM_OFF+0*4096, SM_OFF+1*4096,
        -1, 0.f, 0.f, 1.0f/DVf, NV, NVP, stage, Lorig, Ldst);
  };
  leval(LA_OFF, 1, LB_OFF, 0);
  leval(LB_OFF, 2, LA_OFF, LA_OFF);
  qr(LA_OFF, NVP, 4, NV, SPLIT_QRV, Q1L_OFF, NV, 0, S_OFF, SQRT_DVf, V_OFF, NV, ISQRT_DVf);

  // ---------- outputs: Xe,Se,Ve,Xi,Si,Vi ----------
  float* out = (float*)d_out;
  hipMemcpyAsync(out + 0,       W + X_OFF, FB*(size_t)R*NX, hipMemcpyDeviceToDevice, stream);
  hipMemcpyAsync(out + 1048576, W + S_OFF, FB*(size_t)R*R,  hipMemcpyDeviceToDevice, stream);
  hipMemcpyAsync(out + 1052672, W + V_OFF, FB*(size_t)R*NV, hipMemcpyDeviceToDevice, stream);
  hipMemcpyAsync(out + 1183744, W + (size_t)SPS + X_OFF, FB*(size_t)R*NX, hipMemcpyDeviceToDevice, stream);
  hipMemcpyAsync(out + 2232320, W + (size_t)SPS + S_OFF, FB*(size_t)R*R,  hipMemcpyDeviceToDevice, stream);
  hipMemcpyAsync(out + 2236416, W + (size_t)SPS + V_OFF, FB*(size_t)R*NV, hipMemcpyDeviceToDevice, stream);
  (void)in_sizes; (void)n_in; (void)out_size; (void)ws_size;
}

// Round 2
// 3773.203 us; speedup vs baseline: 2.1983x; 2.1983x over previous
//
#include <hip/hip_runtime.h>

#define R 64
#define NX 16384
#define NV 2048
#define NXP (NX+8)
#define NVP (NV+8)
#define TW 64
#define SPLIT_VM 8
#define SPLIT_X 64
#define SPLIT_QRX 32
#define SPLIT_QRV 8

#define DXf 1.220703125e-4f
#define DVf 0.0078125f
#define DTf 0.001f
#define PI_F 3.14159265358979323846f
#define FAC_E (-1.0f)
#define FAC_I (0.01f)
#define ZE_F (-1.0f)
#define ZI_F (1.0f)
#define SQRT_DXf 0.011048543456039806f
#define SQRT_DVf 0.08838834764831845f
#define ISQRT_DXf 90.50966799187808f
#define ISQRT_DVf 11.313708498984761f

// ---------------- workspace layout (float offsets), per-species stride SPS ----
#define X_OFF 0
#define V_OFF 1048576
#define S_OFF 1179648
#define S1_OFF 1183744
#define SQ_OFF 1187840
#define D_OFF 1191936
#define MATS_OFF 1196032      /* 8 mats: vplus,vminus,Vm,Vp,Vl,Vr,Vmq,Vpq */
#define SM_OFF 1228800        /* KL,KR,EpM,EmM finals */
#define R1D_OFF 1245184       /* f64 64x64 */
#define RFD_OFF 1261568       /* f64 64x64 */
#define R1IF_OFF 1269760      /* f32 */
#define R2IF_OFF 1273856      /* f32 */
#define KA_OFF 1277952        /* 64 x NXP padded */
#define KB_OFF 2327040        /* 64 x NXP padded ; L-phase aliases below */
#define LA_OFF KB_OFF
#define LB_OFF (KB_OFF+131584)
#define Q1L_OFF (KB_OFF+263168)
#define VQ_OFF (KB_OFF+394240)
#define PART_OFF 3376128      /* f32 partials: 4 mats x 64 splits x 4096 */
#define PARTQR_OFF 4424704    /* f64 partials: 32 x 4096 doubles */
#define SPS 4686848
// shared region
#define RHO_OFF 9373696
#define E_OFF 9390080
#define C_OFF 9406464
#define FFT1_OFF 9410560
#define FFT2_OFF 9443328

__device__ __forceinline__ float mm2(float a, float b) {
    return (a*b > 0.0f) ? ((fabsf(a) < fabsf(b)) ? a : b) : 0.0f;
}

// ---------------- generic weighted gram: C[a][b] = sum_x av(a,x)*bv(b,x) ------
// mode 0: 6 V-matrices   mode 1: Vm/Vp masks from Vq   mode 2: K_left/K_right
// mode 3: Ep_mat/Em_mat (weight from fac*E, *DX)
__global__ __launch_bounds__(256) void k_gram(float* W, int mode, int a_off, int lda,
    int b_off, int ldb, int boff, int e_abs, float fac0, float fac1,
    int out_off, int N, int nsplit)
{
  int sp = blockIdx.z, mat = blockIdx.y, split = blockIdx.x;
  float* base = W + (size_t)sp*SPS;
  const float* A = base + a_off;
  const float* B = base + b_off;
  float fac = sp ? fac1 : fac0;
  float* outp = base + out_off + (size_t)(mat*nsplit + split)*4096;
  int chunk = N / nsplit;
  int xb0 = split * chunk;
  __shared__ float tA[TW][R+1], tB[TW][R+1];
  float acc[4][4] = {};
  int tid = threadIdx.x, ty = tid >> 4, tx = tid & 15;
  for (int xt = 0; xt < chunk; xt += TW) {
    for (int idx = tid; idx < TW*R; idx += 256) {
      int xi = idx & 63, r = idx >> 6;
      int x = xb0 + xt + xi;
      float av, bv;
      if (mode == 0) {
        float vv = A[(size_t)r*lda + x];
        float vs = ((float)x + 0.5f)*DVf - 8.0f;
        if (mat == 0)      { av = vv * (fmaxf(vs,0.f)*DVf); bv = vv; }
        else if (mat == 1) { av = vv * (fminf(vs,0.f)*DVf); bv = vv; }
        else if (mat == 2) { av = vv * ((vs<0.f)?DVf:0.f); bv = vv; }
        else if (mat == 3) { av = vv * ((vs>0.f)?DVf:0.f); bv = vv; }
        else if (mat == 4) { av = vv; bv = (x>=1)   ? (vv - A[(size_t)r*lda + x-1]) : 0.f; }
        else               { av = vv; bv = (x<NV-1) ? (A[(size_t)r*lda + x+1] - vv) : 0.f; }
      } else if (mode == 1) {
        float vv = A[(size_t)r*lda + x];
        float vs = ((float)x + 0.5f)*DVf - 8.0f;
        float w = (mat==0) ? ((vs<0.f)?DVf:0.f) : ((vs>0.f)?DVf:0.f);
        av = vv*w; bv = vv;
      } else if (mode == 2) {
        av = A[(size_t)r*lda + x];
        const float* Bp = B + (size_t)r*ldb + boff + x;
        bv = (mat==0) ? (Bp[0] - Bp[-1]) : (Bp[1] - Bp[0]);
      } else {
        float e = W[e_abs + x] * fac;
        float vv = A[(size_t)r*lda + x];
        av = vv * (((mat==0) ? fmaxf(e,0.f) : fminf(e,0.f)) * DXf);
        bv = vv;
      }
      tA[xi][r] = av; tB[xi][r] = bv;
    }
    __syncthreads();
    for (int xi = 0; xi < TW; ++xi) {
      float a0 = tA[xi][ty*4+0], a1 = tA[xi][ty*4+1], a2 = tA[xi][ty*4+2], a3 = tA[xi][ty*4+3];
      float b0 = tB[xi][tx*4+0], b1 = tB[xi][tx*4+1], b2 = tB[xi][tx*4+2], b3 = tB[xi][tx*4+3];
      acc[0][0]+=a0*b0; acc[0][1]+=a0*b1; acc[0][2]+=a0*b2; acc[0][3]+=a0*b3;
      acc[1][0]+=a1*b0; acc[1][1]+=a1*b1; acc[1][2]+=a1*b2; acc[1][3]+=a1*b3;
      acc[2][0]+=a2*b0; acc[2][1]+=a2*b1; acc[2][2]+=a2*b2; acc[2][3]+=a2*b3;
      acc[3][0]+=a3*b0; acc[3][1]+=a3*b1; acc[3][2]+=a3*b2; acc[3][3]+=a3*b3;
    }
    __syncthreads();
  }
  #pragma unroll
  for (int i = 0; i < 4; ++i)
    #pragma unroll
    for (int j = 0; j < 4; ++j)
      outp[(ty*4+i)*64 + tx*4 + j] = acc[i][j];
}

// gram with fp64 accumulation for QR (A only)
__global__ __launch_bounds__(256) void k_gram_qr(float* W, int a_off, int lda, int aoff,
    int N, int nsplit, int outd_off)
{
  int sp = blockIdx.z, split = blockIdx.x;
  float* base = W + (size_t)sp*SPS;
  const float* A = base + a_off + aoff;
  double* outp = (double*)(base + outd_off) + (size_t)split*4096;
  int chunk = N / nsplit, x0 = split*chunk;
  __shared__ float tA[TW][R+1];
  double acc[4][4] = {};
  int tid = threadIdx.x, ty = tid >> 4, tx = tid & 15;
  for (int xt = 0; xt < chunk; xt += TW) {
    for (int idx = tid; idx < TW*R; idx += 256) {
      int xi = idx & 63, r = idx >> 6;
      tA[xi][r] = A[(size_t)r*lda + x0 + xt + xi];
    }
    __syncthreads();
    for (int xi = 0; xi < TW; ++xi) {
      double a0 = tA[xi][ty*4+0], a1 = tA[xi][ty*4+1], a2 = tA[xi][ty*4+2], a3 = tA[xi][ty*4+3];
      double b0 = tA[xi][tx*4+0], b1 = tA[xi][tx*4+1], b2 = tA[xi][tx*4+2], b3 = tA[xi][tx*4+3];
      acc[0][0]+=a0*b0; acc[0][1]+=a0*b1; acc[0][2]+=a0*b2; acc[0][3]+=a0*b3;
      acc[1][0]+=a1*b0; acc[1][1]+=a1*b1; acc[1][2]+=a1*b2; acc[1][3]+=a1*b3;
      acc[2][0]+=a2*b0; acc[2][1]+=a2*b1; acc[2][2]+=a2*b2; acc[2][3]+=a2*b3;
      acc[3][0]+=a3*b0; acc[3][1]+=a3*b1; acc[3][2]+=a3*b2; acc[3][3]+=a3*b3;
    }
    __syncthreads();
  }
  #pragma unroll
  for (int i = 0; i < 4; ++i)
    #pragma unroll
    for (int j = 0; j < 4; ++j)
      outp[(ty*4+i)*64 + tx*4 + j] = acc[i][j];
}

// reduce partial mats
__global__ __launch_bounds__(256) void k_reduce(float* W, int src_off, int dst_off, int nsplit)
{
  int sp = blockIdx.z, mat = blockIdx.x;
  float* base = W + (size_t)sp*SPS;
  const float* src = base + src_off + (size_t)mat*nsplit*4096;
  float* dst = base + dst_off + (size_t)mat*4096;
  for (int e = threadIdx.x; e < 4096; e += 256) {
    float s = 0;
    for (int k = 0; k < nsplit; ++k) s += src[(size_t)k*4096 + e];
    dst[e] = s;
  }
}

// C[j][x] = alpha*d[j]* sum_r coef(r,j) * B[r][x];  coef = transA? A[j][r] : A[r][j]
__global__ __launch_bounds__(256) void k_rr(float* W, int a_off, int transA, int b_off,
    int ldb, int boff, int c_off, int ldc, int coff, int d_off, float alpha)
{
  int sp = blockIdx.z;
  float* base = W + (size_t)sp*SPS;
  const float* A = base + a_off;
  const float* B = base + b_off + boff;
  float* C = base + c_off + coff;
  __shared__ float tA[R][R+1];
  __shared__ float dsc[R];
  int tid = threadIdx.x;
  for (int idx = tid; idx < R*R; idx += 256) {
    int r = idx >> 6, j = idx & 63;
    tA[r][j] = transA ? A[j*R + r] : A[idx];
  }
  if (tid < R) dsc[tid] = (d_off >= 0) ? base[d_off + tid] : 1.0f;
  __syncthreads();
  int ty = tid >> 4, tx = tid & 15;
  int x0 = blockIdx.x*64 + tx*4;
  float acc[4][4] = {};
  for (int r = 0; r < R; ++r) {
    float4 bv = *(const float4*)(B + (size_t)r*ldb + x0);
    float a0 = tA[r][ty*4+0], a1 = tA[r][ty*4+1], a2 = tA[r][ty*4+2], a3 = tA[r][ty*4+3];
    acc[0][0]+=a0*bv.x; acc[0][1]+=a0*bv.y; acc[0][2]+=a0*bv.z; acc[0][3]+=a0*bv.w;
    acc[1][0]+=a1*bv.x; acc[1][1]+=a1*bv.y; acc[1][2]+=a1*bv.z; acc[1][3]+=a1*bv.w;
    acc[2][0]+=a2*bv.x; acc[2][1]+=a2*bv.y; acc[2][2]+=a2*bv.z; acc[2][3]+=a2*bv.w;
    acc[3][0]+=a3*bv.x; acc[3][1]+=a3*bv.y; acc[3][2]+=a3*bv.z; acc[3][3]+=a3*bv.w;
  }
  #pragma unroll
  for (int i = 0; i < 4; ++i) {
    int j = ty*4 + i;
    float s = alpha * dsc[j];
    float4 o = make_float4(acc[i][0]*s, acc[i][1]*s, acc[i][2]*s, acc[i][3]*s);
    *(float4*)(C + (size_t)j*ldc + x0) = o;
  }
}

// ghosts for 2-ghost K buffer: cols 2,3 = Vm@K[:,{1,0}]; NX+4,NX+5 = Vp@K[:,{NX-1,NX-2}]
__global__ __launch_bounds__(256) void k_ghost2(float* W, int k_off)
{
  int sp = blockIdx.z;
  float* base = W + (size_t)sp*SPS;
  float* K = base + k_off;
  int tid = threadIdx.x;
  int j = tid & 63, c = tid >> 6;
  const float* M = base + MATS_OFF + ((c < 2) ? 2 : 3)*4096;
  int dst = (c==0)?2 : (c==1)?3 : (c==2)?(NX+4):(NX+5);
  int src = (c==0)?5 : (c==1)?4 : (c==2)?(NX+3):(NX+2);
  float s = 0;
  for (int m = 0; m < R; ++m) s += M[j*R + m] * K[(size_t)m*NXP + src];
  K[(size_t)j*NXP + dst] = s;
}

// ghosts for 1-ghost K buffer: col 3 = Vm@K[:,0]; NX+4 = Vp@K[:,NX-1]
__global__ __launch_bounds__(128) void k_ghost1(float* W, int k_off, int vm_idx, int vp_idx)
{
  int sp = blockIdx.z;
  float* base = W + (size_t)sp*SPS;
  float* K = base + k_off;
  int tid = threadIdx.x;
  int j = tid & 63, c = tid >> 6;
  const float* M = base + MATS_OFF + ((c==0)? vm_idx : vp_idx)*4096;
  int dst = (c==0)? 3 : (NX+4);
  int src = (c==0)? 4 : (NX+3);
  float s = 0;
  for (int m = 0; m < R; ++m) s += M[j*R + m] * K[(size_t)m*NXP + src];
  K[(size_t)j*NXP + dst] = s;
}

__global__ __launch_bounds__(256) void k_ghostL(float* W)
{
  int sp = blockIdx.z;
  float* base = W + (size_t)sp*SPS;
  for (int idx = threadIdx.x; idx < 512; idx += 256) {
    int which = idx >> 8; int r = (idx >> 2) & 63; int c = idx & 3;
    int col = (c < 2) ? (2 + c) : (NV + 4 + (c - 2));
    (base + (which ? LB_OFF : LA_OFF))[(size_t)r*NVP + col] = 0.f;
  }
}

// fused slope-limited flux divergence + extra term + SSPRK2 combine
__global__ __launch_bounds__(256) void k_flux(float* W, int U_off, int Kx_off, int ldkx,
    int kxoff, int useWin, int P_off, int Mi_off, int A2_off, int B2_off,
    int e_abs, float fac0, float fac1, float dh_inv, int N, int ldp,
    int stage, int orig_off, int out_off)
{
  int sp = blockIdx.z;
  float* base = W + (size_t)sp*SPS;
  const float* U  = base + U_off;
  const float* Kx = base + Kx_off;
  const float* Pm = base + P_off;
  const float* Mm = base + Mi_off;
  const float* Am = base + A2_off;
  const float* Bm = base + B2_off;
  float fac = sp ? fac1 : fac0;
  int x0 = blockIdx.x * 32;
  __shared__ float win[R][37];
  __shared__ float dLt[32][R+1];
  __shared__ float dRt[32][R+1];
  __shared__ float KTt[32][R+1];
  int tid = threadIdx.x;
  for (int idx = tid; idx < R*36; idx += 256) {
    int c = idx % 36, m = idx / 36;
    win[m][c] = U[(size_t)m*ldp + x0 + 2 + c];
  }
  __syncthreads();
  for (int idx = tid; idx < R*32; idx += 256) {
    int xi = idx & 31, m = idx >> 5;
    float u0 = win[m][xi], u1 = win[m][xi+1], u2 = win[m][xi+2], u3 = win[m][xi+3], u4 = win[m][xi+4];
    float d01 = u1-u0, d12 = u2-u1, d23 = u3-u2, d34 = u4-u3;
    float s1 = mm2(d01,d12), s2 = mm2(d12,d23), s3 = mm2(d23,d34);
    dLt[xi][m] = ((u2 + 0.5f*s2) - (u1 + 0.5f*s1)) * dh_inv;
    dRt[xi][m] = ((u3 - 0.5f*s3) - (u2 - 0.5f*s2)) * dh_inv;
    KTt[xi][m] = useWin ? u2 : Kx[(size_t)m*ldkx + kxoff + x0 + xi];
  }
  __syncthreads();
  int ty = tid >> 4, tx = tid & 15;
  int j0 = ty*4;
  float aP[4][2] = {}, aM[4][2] = {}, aA[4][2] = {}, aB[4][2] = {};
  for (int m = 0; m < R; ++m) {
    float dl0 = dLt[tx*2][m],   dl1 = dLt[tx*2+1][m];
    float dr0 = dRt[tx*2][m],   dr1 = dRt[tx*2+1][m];
    float kt0 = KTt[tx*2][m],   kt1 = KTt[tx*2+1][m];
    #pragma unroll
    for (int i = 0; i < 4; ++i) {
      float p = Pm[(j0+i)*R + m], q = Mm[(j0+i)*R + m];
      float a = Am[(j0+i)*R + m], b = Bm[(j0+i)*R + m];
      aP[i][0] += p*dl0; aP[i][1] += p*dl1;
      aM[i][0] += q*dr0; aM[i][1] += q*dr1;
      aA[i][0] += a*kt0; aA[i][1] += a*kt1;
      aB[i][0] += b*kt0; aB[i][1] += b*kt1;
    }
  }
  const float* orig = base + orig_off;
  float* out = base + out_off;
  for (int xx = 0; xx < 2; ++xx) {
    int x = x0 + tx*2 + xx;
    float w1, w2;
    if (e_abs >= 0) { float e = W[e_abs + x]; w1 = fac*fmaxf(e,0.f); w2 = fac*fminf(e,0.f); }
    else { float vs = ((float)x + 0.5f)*DVf - 8.0f; w1 = fmaxf(vs,0.f); w2 = fminf(vs,0.f); }
    #pragma unroll
    for (int i = 0; i < 4; ++i) {
      int j = j0 + i;
      float rhs = -(aP[i][xx] + aM[i][xx] + w1*aA[i][xx] + w2*aB[i][xx]);
      float uval = win[j][tx*2 + xx + 2];
      float res;
      if (stage == 1) res = uval + DTf*rhs;
      else res = 0.5f*(orig[(size_t)j*ldp + 4 + x] + uval + DTf*rhs);
      out[(size_t)j*ldp + 4 + x] = res;
    }
  }
}

// reduce fp64 gram partials + Cholesky + triangular inverse -> R1(f64), R1inv(f32)
// 256 threads: j = tid&63 (column), q = tid>>6 (4-way work split).
// Rule-#20 fix: tri-inverse lives in LDS Wi[][], no runtime-indexed private arrays.
__global__ __launch_bounds__(256) void k_chol1(float* W, int partd_off, int nsplit)
{
  int sp = blockIdx.z;
  float* base = W + (size_t)sp*SPS;
  const double* P = (const double*)(base + partd_off);
  double* R1 = (double*)(base + R1D_OFF);
  float* R1i = base + R1IF_OFF;
  __shared__ double G[R][R+1];
  __shared__ double Wi[R][R+1];
  int tid = threadIdx.x;
  int j = tid & 63, q = tid >> 6;
  // ---- reduce partials: 16 accumulators/thread, 16-deep MLP ----
  {
    double acc[16];
    #pragma unroll
    for (int u = 0; u < 16; ++u) acc[u] = 0.0;
    for (int k = 0; k < nsplit; ++k) {
      const double* Pk = P + (size_t)k*4096 + tid;
      #pragma unroll
      for (int u = 0; u < 16; ++u) acc[u] += Pk[256*u];
    }
    #pragma unroll
    for (int u = 0; u < 16; ++u) {
      int e = tid + 256*u;
      G[e>>6][e&63] = acc[u];
    }
  }
  __syncthreads();
  // ---- Cholesky (upper) ----
  for (int k = 0; k < R; ++k) {
    if (q == 0) {               // wave0 lockstep: all lanes read G[k][k] before any write
      double ukk = sqrt(G[k][k]);
      if (j > k) G[k][j] /= ukk;
      else if (j == k) G[k][k] = ukk;
    }
    __syncthreads();
    if (j > k) {
      double gkj = G[k][j];
      for (int i = k+1+q; i <= j; i += 4) G[i][j] -= G[k][i]*gkj;
    }
    __syncthreads();
  }
  // ---- triangular inverse of upper G -> Wi (LDS, synchronized back-substitution) ----
  if (q == 0) Wi[j][j] = 1.0 / G[j][j];
  __syncthreads();
  for (int i = R-2; i >= 0; --i) {
    if (q == 0 && j > i) {
      double s = 0;
      for (int m = i+1; m <= j; ++m) s += G[i][m]*Wi[m][j];
      Wi[i][j] = -s / G[i][i];
    }
    __syncthreads();
  }
  for (int e = tid; e < 4096; e += 256) {
    int i = e>>6, jj = e&63;
    R1[e]  = (i<=jj) ? G[i][jj] : 0.0;
    R1i[e] = (i<=jj) ? (float)Wi[i][jj] : 0.0f;
  }
}

// reduce G2 + chol -> R2; R2inv; Rf=R2@R1; top-block T; LAPACK sign recursion; S_out
__global__ __launch_bounds__(256) void k_chol2(float* W, int partd_off, int nsplit,
    int q1_off, int ldq, int qoff, int sout_off, float sscale)
{
  int sp = blockIdx.z;
  float* base = W + (size_t)sp*SPS;
  const double* P = (const double*)(base + partd_off);
  const double* R1d = (const double*)(base + R1D_OFF);
  double* RF = (double*)(base + RFD_OFF);
  float* R2i = base + R2IF_OFF;
  const float* Q1 = base + q1_off + qoff;
  __shared__ double G[R][R+1];
  __shared__ double Wi[R][R+1];
  __shared__ double R1s[R][R+1];
  __shared__ float Q1s[R][R+1];
  __shared__ double dsh[R];
  int tid = threadIdx.x;
  int j = tid & 63, q = tid >> 6;
  // ---- reduce partials + stage R1, Q1-top into LDS ----
  {
    double acc[16];
    #pragma unroll
    for (int u = 0; u < 16; ++u) acc[u] = 0.0;
    for (int k = 0; k < nsplit; ++k) {
      const double* Pk = P + (size_t)k*4096 + tid;
      #pragma unroll
      for (int u = 0; u < 16; ++u) acc[u] += Pk[256*u];
    }
    #pragma unroll
    for (int u = 0; u < 16; ++u) {
      int e = tid + 256*u;
      G[e>>6][e&63] = acc[u];
    }
  }
  for (int e = tid; e < 4096; e += 256) {
    int m = e >> 6, x = e & 63;
    R1s[m][x] = R1d[e];
    Q1s[m][x] = Q1[(size_t)m*ldq + x];
  }
  __syncthreads();
  // ---- Cholesky (upper) ----
  for (int k = 0; k < R; ++k) {
    if (q == 0) {
      double ukk = sqrt(G[k][k]);
      if (j > k) G[k][j] /= ukk;
      else if (j == k) G[k][k] = ukk;
    }
    __syncthreads();
    if (j > k) {
      double gkj = G[k][j];
      for (int i = k+1+q; i <= j; i += 4) G[i][j] -= G[k][i]*gkj;
    }
    __syncthreads();
  }
  // ---- triangular inverse -> Wi ----
  if (q == 0) Wi[j][j] = 1.0 / G[j][j];
  __syncthreads();
  for (int i = R-2; i >= 0; --i) {
    if (q == 0 && j > i) {
      double s = 0;
      for (int m = i+1; m <= j; ++m) s += G[i][m]*Wi[m][j];
      Wi[i][j] = -s / G[i][i];
    }
    __syncthreads();
  }
  // ---- RF = R2 @ R1 (i-loop 4-way split over q); R2inv output ----
  for (int i = q; i < R; i += 4) {
    double s = 0;
    if (i <= j) for (int m = i; m <= j; ++m) s += G[i][m] * R1s[m][j];
    RF[i*R + j] = s;
  }
  for (int e = tid; e < 4096; e += 256) {
    int i = e>>6, jj = e&63;
    R2i[e] = (i<=jj) ? (float)Wi[i][jj] : 0.0f;
  }
  __syncthreads();
  // ---- T = Q1top @ R2inv, overwriting G ----
  for (int x = q; x < R; x += 4) {
    double s = 0;
    for (int m = 0; m <= j; ++m) s += Wi[m][j] * (double)Q1s[m][x];
    G[x][j] = s;
  }
  __syncthreads();
  // ---- LAPACK Householder sign chain on exact-orthonormal top block ----
  for (int k = 0; k < R; ++k) {
    double tkk = G[k][k];
    double d = (tkk >= 0.0) ? -1.0 : 1.0;
    if (tid == k) dsh[k] = d;
    if (j > k) {
      double c = d * G[k][j] / (1.0 + fabs(tkk));
      for (int m = k+1+q; m < R; m += 4) G[m][j] += c * G[m][k];
    }
    __syncthreads();
  }
  if (tid < 64) base[D_OFF + tid] = (float)dsh[tid];
  for (int e = tid; e < 4096; e += 256) {
    int i = e >> 6;
    base[sout_off + e] = (float)(dsh[i] * RF[e] * (double)sscale);
  }
}

// S-step small combine: reduce partials, rhs = KL@vp^T + KR@vm^T + fac*(Ep@S@Vl^T + Em@S@Vr^T)
__global__ __launch_bounds__(256) void k_sstep(float* W, int stage)
{
  int sp = blockIdx.x;
  float* base = W + (size_t)sp*SPS;
  const float* part = base + PART_OFF;
  float fac = sp ? FAC_I : FAC_E;
  __shared__ float Ab[4096], Bb[4096], Cb[4096];
  int tid = threadIdx.x, ty = tid >> 4, tx = tid & 15;
  for (int e = tid; e < 4096; e += 256) {
    float s0 = 0, s1 = 0;
    for (int k = 0; k < SPLIT_X; ++k) {
      s0 += part[(size_t)(0*SPLIT_X+k)*4096 + e];
      s1 += part[(size_t)(1*SPLIT_X+k)*4096 + e];
    }
    Ab[e] = s0; Bb[e] = s1;
  }
  __syncthreads();
  const float* vpm = base + MATS_OFF + 0*4096;
  const float* vmm = base + MATS_OFF + 1*4096;
  const float* vlm = base + MATS_OFF + 4*4096;
  const float* vrm = base + MATS_OFF + 5*4096;
  float accV[4][4] = {}, accE[4][4] = {};
  for (int m = 0; m < R; ++m) {
    float kl[4], kr[4], vpj[4], vmj[4];
    #pragma unroll
    for (int i = 0; i < 4; ++i) { kl[i] = Ab[(ty*4+i)*64+m]; kr[i] = Bb[(ty*4+i)*64+m]; }
    #pragma unroll
    for (int j = 0; j < 4; ++j) { vpj[j] = vpm[(tx*4+j)*64+m]; vmj[j] = vmm[(tx*4+j)*64+m]; }
    #pragma unroll
    for (int i = 0; i < 4; ++i)
      #pragma unroll
      for (int j = 0; j < 4; ++j)
        accV[i][j] += kl[i]*vpj[j] + kr[i]*vmj[j];
  }
  __syncthreads();
  const float* Sin = base + ((stage==1)? S_OFF : S1_OFF);
  for (int e = tid; e < 4096; e += 256) Cb[e] = Sin[e];
  for (int e = tid; e < 4096; e += 256) {
    float s = 0;
    for (int k = 0; k < SPLIT_X; ++k) s += part[(size_t)(2*SPLIT_X+k)*4096 + e];
    Ab[e] = s;
  }
  __syncthreads();
  float t1[4][4] = {};
  for (int m = 0; m < R; ++m) {
    float ar[4], cj[4];
    #pragma unroll
    for (int i = 0; i < 4; ++i) ar[i] = Ab[(ty*4+i)*64+m];
    #pragma unroll
    for (int j = 0; j < 4; ++j) cj[j] = Cb[m*64 + tx*4+j];
    #pragma unroll
    for (int i = 0; i < 4; ++i)
      #pragma unroll
      for (int j = 0; j < 4; ++j) t1[i][j] += ar[i]*cj[j];
  }
  __syncthreads();
  #pragma unroll
  for (int i = 0; i < 4; ++i)
    #pragma unroll
    for (int j = 0; j < 4; ++j) Bb[(ty*4+i)*64 + tx*4+j] = t1[i][j];
  __syncthreads();
  for (int m = 0; m < R; ++m) {
    float ar[4], vj[4];
    #pragma unroll
    for (int i = 0; i < 4; ++i) ar[i] = Bb[(ty*4+i)*64+m];
    #pragma unroll
    for (int j = 0; j < 4; ++j) vj[j] = vlm[(tx*4+j)*64+m];
    #pragma unroll
    for (int i = 0; i < 4; ++i)
      #pragma unroll
      for (int j = 0; j < 4; ++j) accE[i][j] += ar[i]*vj[j];
  }
  __syncthreads();
  for (int e = tid; e < 4096; e += 256) {
    float s = 0;
    for (int k = 0; k < SPLIT_X; ++k) s += part[(size_t)(3*SPLIT_X+k)*4096 + e];
    Ab[e] = s;
  }
  __syncthreads();
  float t2[4][4] = {};
  for (int m = 0; m < R; ++m) {
    float ar[4], cj[4];
    #pragma unroll
    for (int i = 0; i < 4; ++i) ar[i] = Ab[(ty*4+i)*64+m];
    #pragma unroll
    for (int j = 0; j < 4; ++j) cj[j] = Cb[m*64 + tx*4+j];
    #pragma unroll
    for (int i = 0; i < 4; ++i)
      #pragma unroll
      for (int j = 0; j < 4; ++j) t2[i][j] += ar[i]*cj[j];
  }
  __syncthreads();
  #pragma unroll
  for (int i = 0; i < 4; ++i)
    #pragma unroll
    for (int j = 0; j < 4; ++j) Bb[(ty*4+i)*64 + tx*4+j] = t2[i][j];
  __syncthreads();
  for (int m = 0; m < R; ++m) {
    float ar[4], vj[4];
    #pragma unroll
    for (int i = 0; i < 4; ++i) ar[i] = Bb[(ty*4+i)*64+m];
    #pragma unroll
    for (int j = 0; j < 4; ++j) vj[j] = vrm[(tx*4+j)*64+m];
    #pragma unroll
    for (int i = 0; i < 4; ++i)
      #pragma unroll
      for (int j = 0; j < 4; ++j) accE[i][j] += ar[i]*vj[j];
  }
  #pragma unroll
  for (int i = 0; i < 4; ++i)
    #pragma unroll
    for (int j = 0; j < 4; ++j) {
      int e = (ty*4+i)*64 + tx*4+j;
      float rhs = accV[i][j] + fac*accE[i][j];
      if (stage == 1) base[S1_OFF + e] = base[S_OFF + e] + DTf*rhs;
      else base[S_OFF + e] = 0.5f*(base[S_OFF + e] + base[S1_OFF + e] + DTf*rhs);
    }
}

// charge moments: c = Z * S @ (V @ 1 * DV)
__global__ __launch_bounds__(256) void k_csolve(float* W)
{
  int sp = blockIdx.x;
  float* base = W + (size_t)sp*SPS;
  const float* V = base + V_OFF;
  const float* S = base + S_OFF;
  __shared__ float red[R][4];
  __shared__ float mass[R];
  int tid = threadIdx.x;
  int r = tid >> 2, q = tid & 3;
  float s = 0;
  for (int v = q; v < NV; v += 4) s += V[(size_t)r*NV + v];
  red[r][q] = s;
  __syncthreads();
  if (tid < R) mass[tid] = (red[tid][0]+red[tid][1]+red[tid][2]+red[tid][3]) * DVf;
  __syncthreads();
  if (tid < R) {
    float c = 0;
    for (int j = 0; j < R; ++j) c += S[tid*R + j] * mass[j];
    W[C_OFF + sp*R + tid] = c * (sp ? ZI_F : ZE_F);
  }
}

__global__ __launch_bounds__(256) void k_rho(float* W)
{
  int x = blockIdx.x*256 + threadIdx.x;
  float s = 0;
  for (int r = 0; r < R; ++r) s += W[X_OFF + (size_t)r*NX + x] * W[C_OFF + r];
  for (int r = 0; r < R; ++r) s += W[(size_t)SPS + X_OFF + (size_t)r*NX + x] * W[C_OFF + R + r];
  W[RHO_OFF + x] = s;
}

// -------- FFT: length-128 radix-2 DIT in LDS, 64 threads --------
__device__ inline void fft128fwd(float2* b, int t)
{
  __syncthreads();
  int r0 = (int)(__brev((unsigned)t) >> 25);
  int r1 = (int)(__brev((unsigned)(t+64)) >> 25);
  float2 a0 = b[r0], a1 = b[r1];
  __syncthreads();
  b[t] = a0; b[t+64] = a1;
  for (int s = 1; s <= 7; ++s) {
    __syncthreads();
    int half = 1 << (s-1);
    int jj = t & (half-1);
    int g  = t >> (s-1);
    int pos = (g << s) + jj;
    float ang = -2.0f*PI_F*(float)jj / (float)(1 << s);
    float sn, cs; sincosf(ang, &sn, &cs);
    float2 u = b[pos], wv = b[pos+half];
    float2 v = make_float2(wv.x*cs - wv.y*sn, wv.x*sn + wv.y*cs);
    b[pos] = make_float2(u.x+v.x, u.y+v.y);
    b[pos+half] = make_float2(u.x-v.x, u.y-v.y);
  }
}

// pass A: per-n1 length-128 FFT over n2 (stride 128) + four-step twiddle, write transposed
__global__ __launch_bounds__(64) void k_fftA(float* W, int rin_off, int cin_off, int out_off)
{
  __shared__ float2 bb[128];
  int n1 = blockIdx.x, t = threadIdx.x;
  if (rin_off >= 0) {
    const float* rin = W + rin_off;
    bb[t]    = make_float2(rin[n1 + 128*t], 0.f);
    bb[t+64] = make_float2(rin[n1 + 128*(t+64)], 0.f);
  } else {
    const float2* cin = (const float2*)(W + cin_off);
    bb[t] = cin[n1 + 128*t]; bb[t+64] = cin[n1 + 128*(t+64)];
  }
  fft128fwd(bb, t);
  __syncthreads();
  float2* outp = (float2*)(W + out_off);
  for (int kk = 0; kk < 2; ++kk) {
    int k2 = t + 64*kk;
    float ang = -2.0f*PI_F*(float)(n1*k2) * (1.0f/16384.0f);
    float sn, cs; sincosf(ang, &sn, &cs);
    float2 v = bb[k2];
    outp[k2*128 + n1] = make_float2(v.x*cs - v.y*sn, v.x*sn + v.y*cs);
  }
}

// pass B: per-k2 FFT over n1; spectral scale 1/(ik); write conj(H) in natural order
__global__ __launch_bounds__(64) void k_fftB(float* W, int in_off, int out_off)
{
  __shared__ float2 bb[128];
  int k2 = blockIdx.x, t = threadIdx.x;
  const float2* in = (const float2*)(W + in_off);
  bb[t] = in[k2*128 + t]; bb[t+64] = in[k2*128 + t + 64];
  fft128fwd(bb, t);
  __syncthreads();
  float2* outp = (float2*)(W + out_off);
  for (int kk = 0; kk < 2; ++kk) {
    int k1 = t + 64*kk;
    int j = k2 + 128*k1;
    float2 X = bb[k1];
    float2 Hc;
    if (j == 0) Hc = make_float2(0.f, 0.f);
    else {
      float kphys = PI_F * (float)((j < 8192) ? j : (j - 16384));
      Hc = make_float2(X.y / kphys, X.x / kphys);   // conj(rho_hat/(i k))
    }
    outp[j] = Hc;
  }
}

// pass D: final FFT pass, take Re()/N -> E
__global__ __launch_bounds__(64) void k_fftD(float* W, int in_off, int e_off)
{
  __shared__ float2 bb[128];
  int k2 = blockIdx.x, t = threadIdx.x;
  const float2* in = (const float2*)(W + in_off);
  bb[t] = in[k2*128 + t]; bb[t+64] = in[k2*128 + t + 64];
  fft128fwd(bb, t);
  __syncthreads();
  for (int kk = 0; kk < 2; ++kk) {
    int k1 = t + 64*kk;
    W[e_off + k2 + 128*k1] = bb[k1].x * (1.0f/16384.0f);
  }
}

// ----------------------------------------------------------------------------
extern "C" void kernel_launch(void* const* d_in, const int* in_sizes, int n_in,
                              void* d_out, int out_size, void* d_ws, size_t ws_size,
                              hipStream_t stream)
{
  float* W = (float*)d_ws;
  const size_t FB = sizeof(float);
  // inputs: Xe, Se, Ve, Xi, Si, Vi
  hipMemcpyAsync(W + X_OFF, d_in[0], FB*(size_t)R*NX, hipMemcpyDeviceToDevice, stream);
  hipMemcpyAsync(W + S_OFF, d_in[1], FB*(size_t)R*R,  hipMemcpyDeviceToDevice, stream);
  hipMemcpyAsync(W + V_OFF, d_in[2], FB*(size_t)R*NV, hipMemcpyDeviceToDevice, stream);
  hipMemcpyAsync(W + (size_t)SPS + X_OFF, d_in[3], FB*(size_t)R*NX, hipMemcpyDeviceToDevice, stream);
  hipMemcpyAsync(W + (size_t)SPS + S_OFF, d_in[4], FB*(size_t)R*R,  hipMemcpyDeviceToDevice, stream);
  hipMemcpyAsync(W + (size_t)SPS + V_OFF, d_in[5], FB*(size_t)R*NV, hipMemcpyDeviceToDevice, stream);

  // V-derived matrices (vplus,vminus,Vm,Vp,Vl,Vr)
  k_gram<<<dim3(SPLIT_VM,6,2),256,0,stream>>>(W, 0, V_OFF, NV, V_OFF, NV, 0, -1, 0.f,0.f, PART_OFF, NV, SPLIT_VM);
  k_reduce<<<dim3(6,1,2),256,0,stream>>>(W, PART_OFF, MATS_OFF, SPLIT_VM);

  auto poisson = [&]() {
    k_csolve<<<dim3(2),256,0,stream>>>(W);
    k_rho<<<dim3(NX/256),256,0,stream>>>(W);
    k_fftA<<<dim3(128),64,0,stream>>>(W, RHO_OFF, -1, FFT1_OFF);
    k_fftB<<<dim3(128),64,0,stream>>>(W, FFT1_OFF, FFT2_OFF);
    k_fftA<<<dim3(128),64,0,stream>>>(W, -1, FFT2_OFF, FFT1_OFF);
    k_fftD<<<dim3(128),64,0,stream>>>(W, FFT1_OFF, E_OFF);
  };

  auto qr = [&](int a_off, int lda, int aoff, int N_, int nsplit,
                int q1_off, int q1_ld, int q1_aoff,
                int sout_off, float sscale, int xout_off, int xout_ld, float inv_s) {
    k_gram_qr<<<dim3(nsplit,1,2),256,0,stream>>>(W, a_off, lda, aoff, N_, nsplit, PARTQR_OFF);
    k_chol1<<<dim3(1,1,2),256,0,stream>>>(W, PARTQR_OFF, nsplit);
    k_rr<<<dim3(N_/64,1,2),256,0,stream>>>(W, R1IF_OFF, 0, a_off, lda, aoff, q1_off, q1_ld, q1_aoff, -1, 1.0f);
    k_gram_qr<<<dim3(nsplit,1,2),256,0,stream>>>(W, q1_off, q1_ld, q1_aoff, N_, nsplit, PARTQR_OFF);
    k_chol2<<<dim3(1,1,2),256,0,stream>>>(W, PARTQR_OFF, nsplit, q1_off, q1_ld, q1_aoff, sout_off, sscale);
    k_rr<<<dim3(N_/64,1,2),256,0,stream>>>(W, R2IF_OFF, 0, q1_off, q1_ld, q1_aoff, xout_off, xout_ld, 0, D_OFF, inv_s);
  };

  // ---------- Poisson #1 + K-step ----------
  poisson();
  k_rr<<<dim3(NX/64,1,2),256,0,stream>>>(W, S_OFF, 0, X_OFF, NX, 0, KA_OFF, NXP, 4, -1, 1.0f);
  k_ghost2<<<dim3(1,1,2),256,0,stream>>>(W, KA_OFF);
  k_flux<<<dim3(NX/32,1,2),256,0,stream>>>(W, KA_OFF, KA_OFF, NXP, 4, 1,
      MATS_OFF+0*4096, MATS_OFF+1*4096, MATS_OFF+4*4096, MATS_OFF+5*4096,
      E_OFF, FAC_E, FAC_I, 1.0f/DXf, NX, NXP, 1, 0, KB_OFF);
  k_ghost2<<<dim3(1,1,2),256,0,stream>>>(W, KB_OFF);
  k_flux<<<dim3(NX/32,1,2),256,0,stream>>>(W, KB_OFF, KB_OFF, NXP, 4, 1,
      MATS_OFF+0*4096, MATS_OFF+1*4096, MATS_OFF+4*4096, MATS_OFF+5*4096,
      E_OFF, FAC_E, FAC_I, 1.0f/DXf, NX, NXP, 2, KA_OFF, KA_OFF);
  qr(KA_OFF, NXP, 4, NX, SPLIT_QRX, KB_OFF, NXP, 4, S_OFF, SQRT_DXf, X_OFF, NX, ISQRT_DXf);

  // ---------- Poisson #2 + S-step ----------
  poisson();
  auto sstep_eval = [&](int stage) {
    int sin = (stage==1) ? S_OFF : S1_OFF;
    k_rr<<<dim3(NX/64,1,2),256,0,stream>>>(W, sin, 0, X_OFF, NX, 0, KA_OFF, NXP, 4, -1, 1.0f);
    k_ghost1<<<dim3(1,1,2),128,0,stream>>>(W, KA_OFF, 2, 3);
    k_gram<<<dim3(SPLIT_X,2,2),256,0,stream>>>(W, 2, X_OFF, NX, KA_OFF, NXP, 4, -1, 0.f,0.f, PART_OFF, NX, SPLIT_X);
    k_gram<<<dim3(SPLIT_X,2,2),256,0,stream>>>(W, 3, X_OFF, NX, 0, 0, 0, E_OFF, 1.0f, 1.0f, PART_OFF + 2*SPLIT_X*4096, NX, SPLIT_X);
    k_sstep<<<dim3(2),256,0,stream>>>(W, stage);
  };
  sstep_eval(1);
  sstep_eval(2);

  // ---------- Poisson #3 + L-step ----------
  poisson();
  k_rr<<<dim3(NV/64,1,2),256,0,stream>>>(W, S_OFF, 1, V_OFF, NV, 0, LA_OFF, NVP, 4, -1, 1.0f);
  k_ghostL<<<dim3(1,1,2),256,0,stream>>>(W);
  auto leval = [&](int Lsrc, int stage, int Ldst, int Lorig) {
    qr(Lsrc, NVP, 4, NV, SPLIT_QRV, Q1L_OFF, NV, 0, SQ_OFF, SQRT_DVf, VQ_OFF, NV, ISQRT_DVf);
    k_gram<<<dim3(SPLIT_VM,2,2),256,0,stream>>>(W, 1, VQ_OFF, NV, VQ_OFF, NV, 0, -1, 0.f,0.f, PART_OFF, NV, SPLIT_VM);
    k_reduce<<<dim3(2,1,2),256,0,stream>>>(W, PART_OFF, MATS_OFF + 6*4096, SPLIT_VM);
    k_rr<<<dim3(NX/64,1,2),256,0,stream>>>(W, SQ_OFF, 0, X_OFF, NX, 0, KA_OFF, NXP, 4, -1, 1.0f);
    k_ghost1<<<dim3(1,1,2),128,0,stream>>>(W, KA_OFF, 6, 7);
    k_gram<<<dim3(SPLIT_X,2,2),256,0,stream>>>(W, 2, X_OFF, NX, KA_OFF, NXP, 4, -1, 0.f,0.f, PART_OFF, NX, SPLIT_X);
    k_gram<<<dim3(SPLIT_X,2,2),256,0,stream>>>(W, 3, X_OFF, NX, 0, 0, 0, E_OFF, FAC_E, FAC_I, PART_OFF + 2*SPLIT_X*4096, NX, SPLIT_X);
    k_reduce<<<dim3(4,1,2),256,0,stream>>>(W, PART_OFF, SM_OFF, SPLIT_X);
    k_flux<<<dim3(NV/32,1,2),256,0,stream>>>(W, Lsrc, VQ_OFF, NV, 0, 0,
        SM_OFF+2*4096, SM_OFF+3*4096, SM_OFF+0*4096, SM_OFF+1*4096,
        -1, 0.f, 0.f, 1.0f/DVf, NV, NVP, stage, Lorig, Ldst);
  };
  leval(LA_OFF, 1, LB_OFF, 0);
  leval(LB_OFF, 2, LA_OFF, LA_OFF);
  qr(LA_OFF, NVP, 4, NV, SPLIT_QRV, Q1L_OFF, NV, 0, S_OFF, SQRT_DVf, V_OFF, NV, ISQRT_DVf);

  // ---------- outputs: Xe,Se,Ve,Xi,Si,Vi ----------
  float* out = (float*)d_out;
  hipMemcpyAsync(out + 0,       W + X_OFF, FB*(size_t)R*NX, hipMemcpyDeviceToDevice, stream);
  hipMemcpyAsync(out + 1048576, W + S_OFF, FB*(size_t)R*R,  hipMemcpyDeviceToDevice, stream);
  hipMemcpyAsync(out + 1052672, W + V_OFF, FB*(size_t)R*NV, hipMemcpyDeviceToDevice, stream);
  hipMemcpyAsync(out + 1183744, W + (size_t)SPS + X_OFF, FB*(size_t)R*NX, hipMemcpyDeviceToDevice, stream);
  hipMemcpyAsync(out + 2232320, W + (size_t)SPS + S_OFF, FB*(size_t)R*R,  hipMemcpyDeviceToDevice, stream);
  hipMemcpyAsync(out + 2236416, W + (size_t)SPS + V_OFF, FB*(size_t)R*NV, hipMemcpyDeviceToDevice, stream);
  (void)in_sizes; (void)n_in; (void)out_size; (void)ws_size;
}

// Round 3
// 2811.832 us; speedup vs baseline: 2.9499x; 1.3419x over previous
//
#include <hip/hip_runtime.h>

#define R 64
#define NX 16384
#define NV 2048
#define NXP (NX+8)
#define NVP (NV+8)
#define TW 64
#define SPLIT_VM 8
#define SPLIT_X 64
#define SPLIT_QRX 32
#define SPLIT_QRV 8

#define DXf 1.220703125e-4f
#define DVf 0.0078125f
#define DTf 0.001f
#define PI_F 3.14159265358979323846f
#define FAC_E (-1.0f)
#define FAC_I (0.01f)
#define ZE_F (-1.0f)
#define ZI_F (1.0f)
#define SQRT_DXf 0.011048543456039806f
#define SQRT_DVf 0.08838834764831845f
#define ISQRT_DXf 90.50966799187808f
#define ISQRT_DVf 11.313708498984761f

// ---------------- workspace layout (float offsets), per-species stride SPS ----
#define X_OFF 0
#define V_OFF 1048576
#define S_OFF 1179648
#define S1_OFF 1183744
#define SQ_OFF 1187840
#define D_OFF 1191936
#define MATS_OFF 1196032      /* 8 mats: vplus,vminus,Vm,Vp,Vl,Vr,Vmq,Vpq */
#define SM_OFF 1228800        /* KL,KR,EpM,EmM finals */
#define R1D_OFF 1245184       /* f64 64x64 */
#define RFD_OFF 1261568       /* f64 64x64 */
#define R1IF_OFF 1269760      /* f32 */
#define R2IF_OFF 1273856      /* f32 */
#define KA_OFF 1277952        /* 64 x NXP padded */
#define KB_OFF 2327040        /* 64 x NXP padded ; L-phase aliases below */
#define LA_OFF KB_OFF
#define LB_OFF (KB_OFF+131584)
#define Q1L_OFF (KB_OFF+263168)
#define VQ_OFF (KB_OFF+394240)
#define PART_OFF 3376128      /* f32 partials: 4 mats x 64 splits x 4096 */
#define PARTQR_OFF 4424704    /* f64 partials: 32 x 4096 doubles */
#define GD_OFF 4686848        /* reduced f64 gram: 4096 doubles = 8192 floats */
#define SPS 4695040
// shared region
#define RHO_OFF 9390080
#define E_OFF 9406464
#define C_OFF 9422848
#define FFT1_OFF 9426944
#define FFT2_OFF 9459712

__device__ __forceinline__ float mm2(float a, float b) {
    return (a*b > 0.0f) ? ((fabsf(a) < fabsf(b)) ? a : b) : 0.0f;
}

// ---------------- generic weighted gram: C[a][b] = sum_x av(a,x)*bv(b,x) ------
// mode 0: 6 V-matrices   mode 1: Vm/Vp masks from Vq   mode 2: K_left/K_right
// mode 3: Ep_mat/Em_mat (weight from fac*E, *DX)
__global__ __launch_bounds__(256) void k_gram(float* W, int mode, int a_off, int lda,
    int b_off, int ldb, int boff, int e_abs, float fac0, float fac1,
    int out_off, int N, int nsplit)
{
  int sp = blockIdx.z, mat = blockIdx.y, split = blockIdx.x;
  float* base = W + (size_t)sp*SPS;
  const float* A = base + a_off;
  const float* B = base + b_off;
  float fac = sp ? fac1 : fac0;
  float* outp = base + out_off + (size_t)(mat*nsplit + split)*4096;
  int chunk = N / nsplit;
  int xb0 = split * chunk;
  __shared__ float tA[TW][R+1], tB[TW][R+1];
  float acc[4][4] = {};
  int tid = threadIdx.x, ty = tid >> 4, tx = tid & 15;
  for (int xt = 0; xt < chunk; xt += TW) {
    for (int idx = tid; idx < TW*R; idx += 256) {
      int xi = idx & 63, r = idx >> 6;
      int x = xb0 + xt + xi;
      float av, bv;
      if (mode == 0) {
        float vv = A[(size_t)r*lda + x];
        float vs = ((float)x + 0.5f)*DVf - 8.0f;
        if (mat == 0)      { av = vv * (fmaxf(vs,0.f)*DVf); bv = vv; }
        else if (mat == 1) { av = vv * (fminf(vs,0.f)*DVf); bv = vv; }
        else if (mat == 2) { av = vv * ((vs<0.f)?DVf:0.f); bv = vv; }
        else if (mat == 3) { av = vv * ((vs>0.f)?DVf:0.f); bv = vv; }
        else if (mat == 4) { av = vv; bv = (x>=1)   ? (vv - A[(size_t)r*lda + x-1]) : 0.f; }
        else               { av = vv; bv = (x<NV-1) ? (A[(size_t)r*lda + x+1] - vv) : 0.f; }
      } else if (mode == 1) {
        float vv = A[(size_t)r*lda + x];
        float vs = ((float)x + 0.5f)*DVf - 8.0f;
        float w = (mat==0) ? ((vs<0.f)?DVf:0.f) : ((vs>0.f)?DVf:0.f);
        av = vv*w; bv = vv;
      } else if (mode == 2) {
        av = A[(size_t)r*lda + x];
        const float* Bp = B + (size_t)r*ldb + boff + x;
        bv = (mat==0) ? (Bp[0] - Bp[-1]) : (Bp[1] - Bp[0]);
      } else {
        float e = W[e_abs + x] * fac;
        float vv = A[(size_t)r*lda + x];
        av = vv * (((mat==0) ? fmaxf(e,0.f) : fminf(e,0.f)) * DXf);
        bv = vv;
      }
      tA[xi][r] = av; tB[xi][r] = bv;
    }
    __syncthreads();
    for (int xi = 0; xi < TW; ++xi) {
      float a0 = tA[xi][ty*4+0], a1 = tA[xi][ty*4+1], a2 = tA[xi][ty*4+2], a3 = tA[xi][ty*4+3];
      float b0 = tB[xi][tx*4+0], b1 = tB[xi][tx*4+1], b2 = tB[xi][tx*4+2], b3 = tB[xi][tx*4+3];
      acc[0][0]+=a0*b0; acc[0][1]+=a0*b1; acc[0][2]+=a0*b2; acc[0][3]+=a0*b3;
      acc[1][0]+=a1*b0; acc[1][1]+=a1*b1; acc[1][2]+=a1*b2; acc[1][3]+=a1*b3;
      acc[2][0]+=a2*b0; acc[2][1]+=a2*b1; acc[2][2]+=a2*b2; acc[2][3]+=a2*b3;
      acc[3][0]+=a3*b0; acc[3][1]+=a3*b1; acc[3][2]+=a3*b2; acc[3][3]+=a3*b3;
    }
    __syncthreads();
  }
  #pragma unroll
  for (int i = 0; i < 4; ++i)
    #pragma unroll
    for (int j = 0; j < 4; ++j)
      outp[(ty*4+i)*64 + tx*4 + j] = acc[i][j];
}

// gram with fp64 accumulation for QR (A only)
__global__ __launch_bounds__(256) void k_gram_qr(float* W, int a_off, int lda, int aoff,
    int N, int nsplit, int outd_off)
{
  int sp = blockIdx.z, split = blockIdx.x;
  float* base = W + (size_t)sp*SPS;
  const float* A = base + a_off + aoff;
  double* outp = (double*)(base + outd_off) + (size_t)split*4096;
  int chunk = N / nsplit, x0 = split*chunk;
  __shared__ float tA[TW][R+1];
  double acc[4][4] = {};
  int tid = threadIdx.x, ty = tid >> 4, tx = tid & 15;
  for (int xt = 0; xt < chunk; xt += TW) {
    for (int idx = tid; idx < TW*R; idx += 256) {
      int xi = idx & 63, r = idx >> 6;
      tA[xi][r] = A[(size_t)r*lda + x0 + xt + xi];
    }
    __syncthreads();
    for (int xi = 0; xi < TW; ++xi) {
      double a0 = tA[xi][ty*4+0], a1 = tA[xi][ty*4+1], a2 = tA[xi][ty*4+2], a3 = tA[xi][ty*4+3];
      double b0 = tA[xi][tx*4+0], b1 = tA[xi][tx*4+1], b2 = tA[xi][tx*4+2], b3 = tA[xi][tx*4+3];
      acc[0][0]+=a0*b0; acc[0][1]+=a0*b1; acc[0][2]+=a0*b2; acc[0][3]+=a0*b3;
      acc[1][0]+=a1*b0; acc[1][1]+=a1*b1; acc[1][2]+=a1*b2; acc[1][3]+=a1*b3;
      acc[2][0]+=a2*b0; acc[2][1]+=a2*b1; acc[2][2]+=a2*b2; acc[2][3]+=a2*b3;
      acc[3][0]+=a3*b0; acc[3][1]+=a3*b1; acc[3][2]+=a3*b2; acc[3][3]+=a3*b3;
    }
    __syncthreads();
  }
  #pragma unroll
  for (int i = 0; i < 4; ++i)
    #pragma unroll
    for (int j = 0; j < 4; ++j)
      outp[(ty*4+i)*64 + tx*4 + j] = acc[i][j];
}

// parallel reduce of f32 partial mats: grid (nmats, 16, 2); 256-elem slice per block
__global__ __launch_bounds__(256) void k_reduce2(float* W, int src_off, int dst_off, int nsplit)
{
  int sp = blockIdx.z, mat = blockIdx.x;
  int e = blockIdx.y*256 + threadIdx.x;
  float* base = W + (size_t)sp*SPS;
  const float* src = base + src_off + (size_t)mat*nsplit*4096 + e;
  float s = 0;
  for (int k = 0; k < nsplit; ++k) s += src[(size_t)k*4096];
  base[dst_off + (size_t)mat*4096 + e] = s;
}

// parallel reduce of f64 QR gram partials: grid (16, 1, 2); 256-elem slice per block
__global__ __launch_bounds__(256) void k_reduced(float* W, int src_off, int dst_off, int nsplit)
{
  int sp = blockIdx.z;
  int e = blockIdx.x*256 + threadIdx.x;
  float* base = W + (size_t)sp*SPS;
  const double* src = (const double*)(base + src_off) + e;
  double s = 0;
  for (int k = 0; k < nsplit; ++k) s += src[(size_t)k*4096];
  ((double*)(base + dst_off))[e] = s;
}

// C[j][x] = alpha*d[j]* sum_r coef(r,j) * B[r][x];  coef = transA? A[j][r] : A[r][j]
__global__ __launch_bounds__(256) void k_rr(float* W, int a_off, int transA, int b_off,
    int ldb, int boff, int c_off, int ldc, int coff, int d_off, float alpha)
{
  int sp = blockIdx.z;
  float* base = W + (size_t)sp*SPS;
  const float* A = base + a_off;
  const float* B = base + b_off + boff;
  float* C = base + c_off + coff;
  __shared__ float tA[R][R+1];
  __shared__ float dsc[R];
  int tid = threadIdx.x;
  for (int idx = tid; idx < R*R; idx += 256) {
    int r = idx >> 6, j = idx & 63;
    tA[r][j] = transA ? A[j*R + r] : A[idx];
  }
  if (tid < R) dsc[tid] = (d_off >= 0) ? base[d_off + tid] : 1.0f;
  __syncthreads();
  int ty = tid >> 4, tx = tid & 15;
  int x0 = blockIdx.x*64 + tx*4;
  float acc[4][4] = {};
  for (int r = 0; r < R; ++r) {
    float4 bv = *(const float4*)(B + (size_t)r*ldb + x0);
    float a0 = tA[r][ty*4+0], a1 = tA[r][ty*4+1], a2 = tA[r][ty*4+2], a3 = tA[r][ty*4+3];
    acc[0][0]+=a0*bv.x; acc[0][1]+=a0*bv.y; acc[0][2]+=a0*bv.z; acc[0][3]+=a0*bv.w;
    acc[1][0]+=a1*bv.x; acc[1][1]+=a1*bv.y; acc[1][2]+=a1*bv.z; acc[1][3]+=a1*bv.w;
    acc[2][0]+=a2*bv.x; acc[2][1]+=a2*bv.y; acc[2][2]+=a2*bv.z; acc[2][3]+=a2*bv.w;
    acc[3][0]+=a3*bv.x; acc[3][1]+=a3*bv.y; acc[3][2]+=a3*bv.z; acc[3][3]+=a3*bv.w;
  }
  #pragma unroll
  for (int i = 0; i < 4; ++i) {
    int j = ty*4 + i;
    float s = alpha * dsc[j];
    float4 o = make_float4(acc[i][0]*s, acc[i][1]*s, acc[i][2]*s, acc[i][3]*s);
    *(float4*)(C + (size_t)j*ldc + x0) = o;
  }
}

// ghosts for 2-ghost K buffer: cols 2,3 = Vm@K[:,{1,0}]; NX+4,NX+5 = Vp@K[:,{NX-1,NX-2}]
__global__ __launch_bounds__(256) void k_ghost2(float* W, int k_off)
{
  int sp = blockIdx.z;
  float* base = W + (size_t)sp*SPS;
  float* K = base + k_off;
  int tid = threadIdx.x;
  int j = tid & 63, c = tid >> 6;
  const float* M = base + MATS_OFF + ((c < 2) ? 2 : 3)*4096;
  int dst = (c==0)?2 : (c==1)?3 : (c==2)?(NX+4):(NX+5);
  int src = (c==0)?5 : (c==1)?4 : (c==2)?(NX+3):(NX+2);
  float s = 0;
  for (int m = 0; m < R; ++m) s += M[j*R + m] * K[(size_t)m*NXP + src];
  K[(size_t)j*NXP + dst] = s;
}

// ghosts for 1-ghost K buffer: col 3 = Vm@K[:,0]; NX+4 = Vp@K[:,NX-1]
__global__ __launch_bounds__(128) void k_ghost1(float* W, int k_off, int vm_idx, int vp_idx)
{
  int sp = blockIdx.z;
  float* base = W + (size_t)sp*SPS;
  float* K = base + k_off;
  int tid = threadIdx.x;
  int j = tid & 63, c = tid >> 6;
  const float* M = base + MATS_OFF + ((c==0)? vm_idx : vp_idx)*4096;
  int dst = (c==0)? 3 : (NX+4);
  int src = (c==0)? 4 : (NX+3);
  float s = 0;
  for (int m = 0; m < R; ++m) s += M[j*R + m] * K[(size_t)m*NXP + src];
  K[(size_t)j*NXP + dst] = s;
}

__global__ __launch_bounds__(256) void k_ghostL(float* W)
{
  int sp = blockIdx.z;
  float* base = W + (size_t)sp*SPS;
  for (int idx = threadIdx.x; idx < 512; idx += 256) {
    int which = idx >> 8; int r = (idx >> 2) & 63; int c = idx & 3;
    int col = (c < 2) ? (2 + c) : (NV + 4 + (c - 2));
    (base + (which ? LB_OFF : LA_OFF))[(size_t)r*NVP + col] = 0.f;
  }
}

// fused slope-limited flux divergence + extra term + SSPRK2 combine
__global__ __launch_bounds__(256) void k_flux(float* W, int U_off, int Kx_off, int ldkx,
    int kxoff, int useWin, int P_off, int Mi_off, int A2_off, int B2_off,
    int e_abs, float fac0, float fac1, float dh_inv, int N, int ldp,
    int stage, int orig_off, int out_off)
{
  int sp = blockIdx.z;
  float* base = W + (size_t)sp*SPS;
  const float* U  = base + U_off;
  const float* Kx = base + Kx_off;
  const float* Pm = base + P_off;
  const float* Mm = base + Mi_off;
  const float* Am = base + A2_off;
  const float* Bm = base + B2_off;
  float fac = sp ? fac1 : fac0;
  int x0 = blockIdx.x * 32;
  __shared__ float win[R][37];
  __shared__ float dLt[32][R+1];
  __shared__ float dRt[32][R+1];
  __shared__ float KTt[32][R+1];
  int tid = threadIdx.x;
  for (int idx = tid; idx < R*36; idx += 256) {
    int c = idx % 36, m = idx / 36;
    win[m][c] = U[(size_t)m*ldp + x0 + 2 + c];
  }
  __syncthreads();
  for (int idx = tid; idx < R*32; idx += 256) {
    int xi = idx & 31, m = idx >> 5;
    float u0 = win[m][xi], u1 = win[m][xi+1], u2 = win[m][xi+2], u3 = win[m][xi+3], u4 = win[m][xi+4];
    float d01 = u1-u0, d12 = u2-u1, d23 = u3-u2, d34 = u4-u3;
    float s1 = mm2(d01,d12), s2 = mm2(d12,d23), s3 = mm2(d23,d34);
    dLt[xi][m] = ((u2 + 0.5f*s2) - (u1 + 0.5f*s1)) * dh_inv;
    dRt[xi][m] = ((u3 - 0.5f*s3) - (u2 - 0.5f*s2)) * dh_inv;
    KTt[xi][m] = useWin ? u2 : Kx[(size_t)m*ldkx + kxoff + x0 + xi];
  }
  __syncthreads();
  int ty = tid >> 4, tx = tid & 15;
  int j0 = ty*4;
  float aP[4][2] = {}, aM[4][2] = {}, aA[4][2] = {}, aB[4][2] = {};
  for (int m = 0; m < R; ++m) {
    float dl0 = dLt[tx*2][m],   dl1 = dLt[tx*2+1][m];
    float dr0 = dRt[tx*2][m],   dr1 = dRt[tx*2+1][m];
    float kt0 = KTt[tx*2][m],   kt1 = KTt[tx*2+1][m];
    #pragma unroll
    for (int i = 0; i < 4; ++i) {
      float p = Pm[(j0+i)*R + m], q = Mm[(j0+i)*R + m];
      float a = Am[(j0+i)*R + m], b = Bm[(j0+i)*R + m];
      aP[i][0] += p*dl0; aP[i][1] += p*dl1;
      aM[i][0] += q*dr0; aM[i][1] += q*dr1;
      aA[i][0] += a*kt0; aA[i][1] += a*kt1;
      aB[i][0] += b*kt0; aB[i][1] += b*kt1;
    }
  }
  const float* orig = base + orig_off;
  float* out = base + out_off;
  for (int xx = 0; xx < 2; ++xx) {
    int x = x0 + tx*2 + xx;
    float w1, w2;
    if (e_abs >= 0) { float e = W[e_abs + x]; w1 = fac*fmaxf(e,0.f); w2 = fac*fminf(e,0.f); }
    else { float vs = ((float)x + 0.5f)*DVf - 8.0f; w1 = fmaxf(vs,0.f); w2 = fminf(vs,0.f); }
    #pragma unroll
    for (int i = 0; i < 4; ++i) {
      int j = j0 + i;
      float rhs = -(aP[i][xx] + aM[i][xx] + w1*aA[i][xx] + w2*aB[i][xx]);
      float uval = win[j][tx*2 + xx + 2];
      float res;
      if (stage == 1) res = uval + DTf*rhs;
      else res = 0.5f*(orig[(size_t)j*ldp + 4 + x] + uval + DTf*rhs);
      out[(size_t)j*ldp + 4 + x] = res;
    }
  }
}

// Cholesky + triangular inverse from reduced f64 gram -> R1(f64), R1inv(f32)
__global__ __launch_bounds__(256) void k_chol1(float* W, int gd_off)
{
  int sp = blockIdx.z;
  float* base = W + (size_t)sp*SPS;
  const double* GD = (const double*)(base + gd_off);
  double* R1 = (double*)(base + R1D_OFF);
  float* R1i = base + R1IF_OFF;
  __shared__ double G[R][R+1];
  __shared__ double Wi[R][R+1];
  int tid = threadIdx.x;
  int j = tid & 63, q = tid >> 6;
  for (int e = tid; e < 4096; e += 256) G[e>>6][e&63] = GD[e];
  __syncthreads();
  // ---- Cholesky (upper) ----
  for (int k = 0; k < R; ++k) {
    if (q == 0) {               // wave0 lockstep: all lanes read G[k][k] before any write
      double ukk = sqrt(G[k][k]);
      if (j > k) G[k][j] /= ukk;
      else if (j == k) G[k][k] = ukk;
    }
    __syncthreads();
    if (j > k) {
      double gkj = G[k][j];
      for (int i = k+1+q; i <= j; i += 4) G[i][j] -= G[k][i]*gkj;
    }
    __syncthreads();
  }
  // ---- triangular inverse of upper G -> Wi (LDS, synchronized back-substitution) ----
  if (q == 0) Wi[j][j] = 1.0 / G[j][j];
  __syncthreads();
  for (int i = R-2; i >= 0; --i) {
    if (q == 0 && j > i) {
      double s = 0;
      for (int m = i+1; m <= j; ++m) s += G[i][m]*Wi[m][j];
      Wi[i][j] = -s / G[i][i];
    }
    __syncthreads();
  }
  for (int e = tid; e < 4096; e += 256) {
    int i = e>>6, jj = e&63;
    R1[e]  = (i<=jj) ? G[i][jj] : 0.0;
    R1i[e] = (i<=jj) ? (float)Wi[i][jj] : 0.0f;
  }
}

// chol of reduced G2 -> R2; R2inv; Rf=R2@R1; top-block T; LAPACK sign recursion; S_out
__global__ __launch_bounds__(256) void k_chol2(float* W, int gd_off,
    int q1_off, int ldq, int qoff, int sout_off, float sscale)
{
  int sp = blockIdx.z;
  float* base = W + (size_t)sp*SPS;
  const double* GD = (const double*)(base + gd_off);
  const double* R1d = (const double*)(base + R1D_OFF);
  double* RF = (double*)(base + RFD_OFF);
  float* R2i = base + R2IF_OFF;
  const float* Q1 = base + q1_off + qoff;
  __shared__ double G[R][R+1];
  __shared__ double Wi[R][R+1];
  __shared__ double R1s[R][R+1];
  __shared__ float Q1s[R][R+1];
  __shared__ double dsh[R];
  int tid = threadIdx.x;
  int j = tid & 63, q = tid >> 6;
  for (int e = tid; e < 4096; e += 256) G[e>>6][e&63] = GD[e];
  for (int e = tid; e < 4096; e += 256) {
    int m = e >> 6, x = e & 63;
    R1s[m][x] = R1d[e];
    Q1s[m][x] = Q1[(size_t)m*ldq + x];
  }
  __syncthreads();
  // ---- Cholesky (upper) ----
  for (int k = 0; k < R; ++k) {
    if (q == 0) {
      double ukk = sqrt(G[k][k]);
      if (j > k) G[k][j] /= ukk;
      else if (j == k) G[k][k] = ukk;
    }
    __syncthreads();
    if (j > k) {
      double gkj = G[k][j];
      for (int i = k+1+q; i <= j; i += 4) G[i][j] -= G[k][i]*gkj;
    }
    __syncthreads();
  }
  // ---- triangular inverse -> Wi ----
  if (q == 0) Wi[j][j] = 1.0 / G[j][j];
  __syncthreads();
  for (int i = R-2; i >= 0; --i) {
    if (q == 0 && j > i) {
      double s = 0;
      for (int m = i+1; m <= j; ++m) s += G[i][m]*Wi[m][j];
      Wi[i][j] = -s / G[i][i];
    }
    __syncthreads();
  }
  // ---- RF = R2 @ R1 (i-loop 4-way split over q); R2inv output ----
  for (int i = q; i < R; i += 4) {
    double s = 0;
    if (i <= j) for (int m = i; m <= j; ++m) s += G[i][m] * R1s[m][j];
    RF[i*R + j] = s;
  }
  for (int e = tid; e < 4096; e += 256) {
    int i = e>>6, jj = e&63;
    R2i[e] = (i<=jj) ? (float)Wi[i][jj] : 0.0f;
  }
  __syncthreads();
  // ---- T = Q1top @ R2inv, overwriting G ----
  for (int x = q; x < R; x += 4) {
    double s = 0;
    for (int m = 0; m <= j; ++m) s += Wi[m][j] * (double)Q1s[m][x];
    G[x][j] = s;
  }
  __syncthreads();
  // ---- LAPACK Householder sign chain on exact-orthonormal top block ----
  for (int k = 0; k < R; ++k) {
    double tkk = G[k][k];
    double d = (tkk >= 0.0) ? -1.0 : 1.0;
    if (tid == k) dsh[k] = d;
    if (j > k) {
      double c = d * G[k][j] / (1.0 + fabs(tkk));
      for (int m = k+1+q; m < R; m += 4) G[m][j] += c * G[m][k];
    }
    __syncthreads();
  }
  if (tid < 64) base[D_OFF + tid] = (float)dsh[tid];
  for (int e = tid; e < 4096; e += 256) {
    int i = e >> 6;
    base[sout_off + e] = (float)(dsh[i] * RF[e] * (double)sscale);
  }
}

// S-step small combine from pre-reduced mats at SM_OFF:
// rhs = KL@vp^T + KR@vm^T + fac*(Ep@S@Vl^T + Em@S@Vr^T)
__global__ __launch_bounds__(256) void k_sstep(float* W, int stage)
{
  int sp = blockIdx.x;
  float* base = W + (size_t)sp*SPS;
  float fac = sp ? FAC_I : FAC_E;
  __shared__ float Ab[4096], Bb[4096], Cb[4096];
  int tid = threadIdx.x, ty = tid >> 4, tx = tid & 15;
  for (int e = tid; e < 4096; e += 256) {
    Ab[e] = base[SM_OFF + e];            // KL
    Bb[e] = base[SM_OFF + 4096 + e];     // KR
  }
  __syncthreads();
  const float* vpm = base + MATS_OFF + 0*4096;
  const float* vmm = base + MATS_OFF + 1*4096;
  const float* vlm = base + MATS_OFF + 4*4096;
  const float* vrm = base + MATS_OFF + 5*4096;
  float accV[4][4] = {}, accE[4][4] = {};
  for (int m = 0; m < R; ++m) {
    float kl[4], kr[4], vpj[4], vmj[4];
    #pragma unroll
    for (int i = 0; i < 4; ++i) { kl[i] = Ab[(ty*4+i)*64+m]; kr[i] = Bb[(ty*4+i)*64+m]; }
    #pragma unroll
    for (int j = 0; j < 4; ++j) { vpj[j] = vpm[(tx*4+j)*64+m]; vmj[j] = vmm[(tx*4+j)*64+m]; }
    #pragma unroll
    for (int i = 0; i < 4; ++i)
      #pragma unroll
      for (int j = 0; j < 4; ++j)
        accV[i][j] += kl[i]*vpj[j] + kr[i]*vmj[j];
  }
  __syncthreads();
  const float* Sin = base + ((stage==1)? S_OFF : S1_OFF);
  for (int e = tid; e < 4096; e += 256) {
    Cb[e] = Sin[e];
    Ab[e] = base[SM_OFF + 2*4096 + e];   // Ep_mat
  }
  __syncthreads();
  float t1[4][4] = {};
  for (int m = 0; m < R; ++m) {
    float ar[4], cj[4];
    #pragma unroll
    for (int i = 0; i < 4; ++i) ar[i] = Ab[(ty*4+i)*64+m];
    #pragma unroll
    for (int j = 0; j < 4; ++j) cj[j] = Cb[m*64 + tx*4+j];
    #pragma unroll
    for (int i = 0; i < 4; ++i)
      #pragma unroll
      for (int j = 0; j < 4; ++j) t1[i][j] += ar[i]*cj[j];
  }
  __syncthreads();
  #pragma unroll
  for (int i = 0; i < 4; ++i)
    #pragma unroll
    for (int j = 0; j < 4; ++j) Bb[(ty*4+i)*64 + tx*4+j] = t1[i][j];
  __syncthreads();
  for (int m = 0; m < R; ++m) {
    float ar[4], vj[4];
    #pragma unroll
    for (int i = 0; i < 4; ++i) ar[i] = Bb[(ty*4+i)*64+m];
    #pragma unroll
    for (int j = 0; j < 4; ++j) vj[j] = vlm[(tx*4+j)*64+m];
    #pragma unroll
    for (int i = 0; i < 4; ++i)
      #pragma unroll
      for (int j = 0; j < 4; ++j) accE[i][j] += ar[i]*vj[j];
  }
  __syncthreads();
  for (int e = tid; e < 4096; e += 256) Ab[e] = base[SM_OFF + 3*4096 + e];  // Em_mat
  __syncthreads();
  float t2[4][4] = {};
  for (int m = 0; m < R; ++m) {
    float ar[4], cj[4];
    #pragma unroll
    for (int i = 0; i < 4; ++i) ar[i] = Ab[(ty*4+i)*64+m];
    #pragma unroll
    for (int j = 0; j < 4; ++j) cj[j] = Cb[m*64 + tx*4+j];
    #pragma unroll
    for (int i = 0; i < 4; ++i)
      #pragma unroll
      for (int j = 0; j < 4; ++j) t2[i][j] += ar[i]*cj[j];
  }
  __syncthreads();
  #pragma unroll
  for (int i = 0; i < 4; ++i)
    #pragma unroll
    for (int j = 0; j < 4; ++j) Bb[(ty*4+i)*64 + tx*4+j] = t2[i][j];
  __syncthreads();
  for (int m = 0; m < R; ++m) {
    float ar[4], vj[4];
    #pragma unroll
    for (int i = 0; i < 4; ++i) ar[i] = Bb[(ty*4+i)*64+m];
    #pragma unroll
    for (int j = 0; j < 4; ++j) vj[j] = vrm[(tx*4+j)*64+m];
    #pragma unroll
    for (int i = 0; i < 4; ++i)
      #pragma unroll
      for (int j = 0; j < 4; ++j) accE[i][j] += ar[i]*vj[j];
  }
  #pragma unroll
  for (int i = 0; i < 4; ++i)
    #pragma unroll
    for (int j = 0; j < 4; ++j) {
      int e = (ty*4+i)*64 + tx*4+j;
      float rhs = accV[i][j] + fac*accE[i][j];
      if (stage == 1) base[S1_OFF + e] = base[S_OFF + e] + DTf*rhs;
      else base[S_OFF + e] = 0.5f*(base[S_OFF + e] + base[S1_OFF + e] + DTf*rhs);
    }
}

// charge moments: c = Z * S @ (V @ 1 * DV)
__global__ __launch_bounds__(256) void k_csolve(float* W)
{
  int sp = blockIdx.x;
  float* base = W + (size_t)sp*SPS;
  const float* V = base + V_OFF;
  const float* S = base + S_OFF;
  __shared__ float red[R][4];
  __shared__ float mass[R];
  int tid = threadIdx.x;
  int r = tid >> 2, q = tid & 3;
  float s = 0;
  for (int v = q; v < NV; v += 4) s += V[(size_t)r*NV + v];
  red[r][q] = s;
  __syncthreads();
  if (tid < R) mass[tid] = (red[tid][0]+red[tid][1]+red[tid][2]+red[tid][3]) * DVf;
  __syncthreads();
  if (tid < R) {
    float c = 0;
    for (int j = 0; j < R; ++j) c += S[tid*R + j] * mass[j];
    W[C_OFF + sp*R + tid] = c * (sp ? ZI_F : ZE_F);
  }
}

__global__ __launch_bounds__(256) void k_rho(float* W)
{
  int x = blockIdx.x*256 + threadIdx.x;
  float s = 0;
  for (int r = 0; r < R; ++r) s += W[X_OFF + (size_t)r*NX + x] * W[C_OFF + r];
  for (int r = 0; r < R; ++r) s += W[(size_t)SPS + X_OFF + (size_t)r*NX + x] * W[C_OFF + R + r];
  W[RHO_OFF + x] = s;
}

// -------- FFT: length-128 radix-2 DIT in LDS, 64 threads --------
__device__ inline void fft128fwd(float2* b, int t)
{
  __syncthreads();
  int r0 = (int)(__brev((unsigned)t) >> 25);
  int r1 = (int)(__brev((unsigned)(t+64)) >> 25);
  float2 a0 = b[r0], a1 = b[r1];
  __syncthreads();
  b[t] = a0; b[t+64] = a1;
  for (int s = 1; s <= 7; ++s) {
    __syncthreads();
    int half = 1 << (s-1);
    int jj = t & (half-1);
    int g  = t >> (s-1);
    int pos = (g << s) + jj;
    float ang = -2.0f*PI_F*(float)jj / (float)(1 << s);
    float sn, cs; sincosf(ang, &sn, &cs);
    float2 u = b[pos], wv = b[pos+half];
    float2 v = make_float2(wv.x*cs - wv.y*sn, wv.x*sn + wv.y*cs);
    b[pos] = make_float2(u.x+v.x, u.y+v.y);
    b[pos+half] = make_float2(u.x-v.x, u.y-v.y);
  }
}

// pass A: per-n1 length-128 FFT over n2 (stride 128) + four-step twiddle, write transposed
__global__ __launch_bounds__(64) void k_fftA(float* W, int rin_off, int cin_off, int out_off)
{
  __shared__ float2 bb[128];
  int n1 = blockIdx.x, t = threadIdx.x;
  if (rin_off >= 0) {
    const float* rin = W + rin_off;
    bb[t]    = make_float2(rin[n1 + 128*t], 0.f);
    bb[t+64] = make_float2(rin[n1 + 128*(t+64)], 0.f);
  } else {
    const float2* cin = (const float2*)(W + cin_off);
    bb[t] = cin[n1 + 128*t]; bb[t+64] = cin[n1 + 128*(t+64)];
  }
  fft128fwd(bb, t);
  __syncthreads();
  float2* outp = (float2*)(W + out_off);
  for (int kk = 0; kk < 2; ++kk) {
    int k2 = t + 64*kk;
    float ang = -2.0f*PI_F*(float)(n1*k2) * (1.0f/16384.0f);
    float sn, cs; sincosf(ang, &sn, &cs);
    float2 v = bb[k2];
    outp[k2*128 + n1] = make_float2(v.x*cs - v.y*sn, v.x*sn + v.y*cs);
  }
}

// pass B: per-k2 FFT over n1; spectral scale 1/(ik); write conj(H) in natural order
__global__ __launch_bounds__(64) void k_fftB(float* W, int in_off, int out_off)
{
  __shared__ float2 bb[128];
  int k2 = blockIdx.x, t = threadIdx.x;
  const float2* in = (const float2*)(W + in_off);
  bb[t] = in[k2*128 + t]; bb[t+64] = in[k2*128 + t + 64];
  fft128fwd(bb, t);
  __syncthreads();
  float2* outp = (float2*)(W + out_off);
  for (int kk = 0; kk < 2; ++kk) {
    int k1 = t + 64*kk;
    int j = k2 + 128*k1;
    float2 X = bb[k1];
    float2 Hc;
    if (j == 0) Hc = make_float2(0.f, 0.f);
    else {
      float kphys = PI_F * (float)((j < 8192) ? j : (j - 16384));
      Hc = make_float2(X.y / kphys, X.x / kphys);   // conj(rho_hat/(i k))
    }
    outp[j] = Hc;
  }
}

// pass D: final FFT pass, take Re()/N -> E
__global__ __launch_bounds__(64) void k_fftD(float* W, int in_off, int e_off)
{
  __shared__ float2 bb[128];
  int k2 = blockIdx.x, t = threadIdx.x;
  const float2* in = (const float2*)(W + in_off);
  bb[t] = in[k2*128 + t]; bb[t+64] = in[k2*128 + t + 64];
  fft128fwd(bb, t);
  __syncthreads();
  for (int kk = 0; kk < 2; ++kk) {
    int k1 = t + 64*kk;
    W[e_off + k2 + 128*k1] = bb[k1].x * (1.0f/16384.0f);
  }
}

// ----------------------------------------------------------------------------
extern "C" void kernel_launch(void* const* d_in, const int* in_sizes, int n_in,
                              void* d_out, int out_size, void* d_ws, size_t ws_size,
                              hipStream_t stream)
{
  float* W = (float*)d_ws;
  const size_t FB = sizeof(float);
  // inputs: Xe, Se, Ve, Xi, Si, Vi
  hipMemcpyAsync(W + X_OFF, d_in[0], FB*(size_t)R*NX, hipMemcpyDeviceToDevice, stream);
  hipMemcpyAsync(W + S_OFF, d_in[1], FB*(size_t)R*R,  hipMemcpyDeviceToDevice, stream);
  hipMemcpyAsync(W + V_OFF, d_in[2], FB*(size_t)R*NV, hipMemcpyDeviceToDevice, stream);
  hipMemcpyAsync(W + (size_t)SPS + X_OFF, d_in[3], FB*(size_t)R*NX, hipMemcpyDeviceToDevice, stream);
  hipMemcpyAsync(W + (size_t)SPS + S_OFF, d_in[4], FB*(size_t)R*R,  hipMemcpyDeviceToDevice, stream);
  hipMemcpyAsync(W + (size_t)SPS + V_OFF, d_in[5], FB*(size_t)R*NV, hipMemcpyDeviceToDevice, stream);

  // V-derived matrices (vplus,vminus,Vm,Vp,Vl,Vr)
  k_gram<<<dim3(SPLIT_VM,6,2),256,0,stream>>>(W, 0, V_OFF, NV, V_OFF, NV, 0, -1, 0.f,0.f, PART_OFF, NV, SPLIT_VM);
  k_reduce2<<<dim3(6,16,2),256,0,stream>>>(W, PART_OFF, MATS_OFF, SPLIT_VM);

  auto poisson = [&]() {
    k_csolve<<<dim3(2),256,0,stream>>>(W);
    k_rho<<<dim3(NX/256),256,0,stream>>>(W);
    k_fftA<<<dim3(128),64,0,stream>>>(W, RHO_OFF, -1, FFT1_OFF);
    k_fftB<<<dim3(128),64,0,stream>>>(W, FFT1_OFF, FFT2_OFF);
    k_fftA<<<dim3(128),64,0,stream>>>(W, -1, FFT2_OFF, FFT1_OFF);
    k_fftD<<<dim3(128),64,0,stream>>>(W, FFT1_OFF, E_OFF);
  };

  auto qr = [&](int a_off, int lda, int aoff, int N_, int nsplit,
                int q1_off, int q1_ld, int q1_aoff,
                int sout_off, float sscale, int xout_off, int xout_ld, float inv_s) {
    k_gram_qr<<<dim3(nsplit,1,2),256,0,stream>>>(W, a_off, lda, aoff, N_, nsplit, PARTQR_OFF);
    k_reduced<<<dim3(16,1,2),256,0,stream>>>(W, PARTQR_OFF, GD_OFF, nsplit);
    k_chol1<<<dim3(1,1,2),256,0,stream>>>(W, GD_OFF);
    k_rr<<<dim3(N_/64,1,2),256,0,stream>>>(W, R1IF_OFF, 0, a_off, lda, aoff, q1_off, q1_ld, q1_aoff, -1, 1.0f);
    k_gram_qr<<<dim3(nsplit,1,2),256,0,stream>>>(W, q1_off, q1_ld, q1_aoff, N_, nsplit, PARTQR_OFF);
    k_reduced<<<dim3(16,1,2),256,0,stream>>>(W, PARTQR_OFF, GD_OFF, nsplit);
    k_chol2<<<dim3(1,1,2),256,0,stream>>>(W, GD_OFF, q1_off, q1_ld, q1_aoff, sout_off, sscale);
    k_rr<<<dim3(N_/64,1,2),256,0,stream>>>(W, R2IF_OFF, 0, q1_off, q1_ld, q1_aoff, xout_off, xout_ld, 0, D_OFF, inv_s);
  };

  // ---------- Poisson #1 + K-step ----------
  poisson();
  k_rr<<<dim3(NX/64,1,2),256,0,stream>>>(W, S_OFF, 0, X_OFF, NX, 0, KA_OFF, NXP, 4, -1, 1.0f);
  k_ghost2<<<dim3(1,1,2),256,0,stream>>>(W, KA_OFF);
  k_flux<<<dim3(NX/32,1,2),256,0,stream>>>(W, KA_OFF, KA_OFF, NXP, 4, 1,
      MATS_OFF+0*4096, MATS_OFF+1*4096, MATS_OFF+4*4096, MATS_OFF+5*4096,
      E_OFF, FAC_E, FAC_I, 1.0f/DXf, NX, NXP, 1, 0, KB_OFF);
  k_ghost2<<<dim3(1,1,2),256,0,stream>>>(W, KB_OFF);
  k_flux<<<dim3(NX/32,1,2),256,0,stream>>>(W, KB_OFF, KB_OFF, NXP, 4, 1,
      MATS_OFF+0*4096, MATS_OFF+1*4096, MATS_OFF+4*4096, MATS_OFF+5*4096,
      E_OFF, FAC_E, FAC_I, 1.0f/DXf, NX, NXP, 2, KA_OFF, KA_OFF);
  qr(KA_OFF, NXP, 4, NX, SPLIT_QRX, KB_OFF, NXP, 4, S_OFF, SQRT_DXf, X_OFF, NX, ISQRT_DXf);

  // ---------- Poisson #2 + S-step ----------
  poisson();
  auto sstep_eval = [&](int stage) {
    int sin = (stage==1) ? S_OFF : S1_OFF;
    k_rr<<<dim3(NX/64,1,2),256,0,stream>>>(W, sin, 0, X_OFF, NX, 0, KA_OFF, NXP, 4, -1, 1.0f);
    k_ghost1<<<dim3(1,1,2),128,0,stream>>>(W, KA_OFF, 2, 3);
    k_gram<<<dim3(SPLIT_X,2,2),256,0,stream>>>(W, 2, X_OFF, NX, KA_OFF, NXP, 4, -1, 0.f,0.f, PART_OFF, NX, SPLIT_X);
    k_gram<<<dim3(SPLIT_X,2,2),256,0,stream>>>(W, 3, X_OFF, NX, 0, 0, 0, E_OFF, 1.0f, 1.0f, PART_OFF + 2*SPLIT_X*4096, NX, SPLIT_X);
    k_reduce2<<<dim3(4,16,2),256,0,stream>>>(W, PART_OFF, SM_OFF, SPLIT_X);
    k_sstep<<<dim3(2),256,0,stream>>>(W, stage);
  };
  sstep_eval(1);
  sstep_eval(2);

  // ---------- Poisson #3 + L-step ----------
  poisson();
  k_rr<<<dim3(NV/64,1,2),256,0,stream>>>(W, S_OFF, 1, V_OFF, NV, 0, LA_OFF, NVP, 4, -1, 1.0f);
  k_ghostL<<<dim3(1,1,2),256,0,stream>>>(W);
  auto leval = [&](int Lsrc, int stage, int Ldst, int Lorig) {
    qr(Lsrc, NVP, 4, NV, SPLIT_QRV, Q1L_OFF, NV, 0, SQ_OFF, SQRT_DVf, VQ_OFF, NV, ISQRT_DVf);
    k_gram<<<dim3(SPLIT_VM,2,2),256,0,stream>>>(W, 1, VQ_OFF, NV, VQ_OFF, NV, 0, -1, 0.f,0.f, PART_OFF, NV, SPLIT_VM);
    k_reduce2<<<dim3(2,16,2),256,0,stream>>>(W, PART_OFF, MATS_OFF + 6*4096, SPLIT_VM);
    k_rr<<<dim3(NX/64,1,2),256,0,stream>>>(W, SQ_OFF, 0, X_OFF, NX, 0, KA_OFF, NXP, 4, -1, 1.0f);
    k_ghost1<<<dim3(1,1,2),128,0,stream>>>(W, KA_OFF, 6, 7);
    k_gram<<<dim3(SPLIT_X,2,2),256,0,stream>>>(W, 2, X_OFF, NX, KA_OFF, NXP, 4, -1, 0.f,0.f, PART_OFF, NX, SPLIT_X);
    k_gram<<<dim3(SPLIT_X,2,2),256,0,stream>>>(W, 3, X_OFF, NX, 0, 0, 0, E_OFF, FAC_E, FAC_I, PART_OFF + 2*SPLIT_X*4096, NX, SPLIT_X);
    k_reduce2<<<dim3(4,16,2),256,0,stream>>>(W, PART_OFF, SM_OFF, SPLIT_X);
    k_flux<<<dim3(NV/32,1,2),256,0,stream>>>(W, Lsrc, VQ_OFF, NV, 0, 0,
        SM_OFF+2*4096, SM_OFF+3*4096, SM_OFF+0*4096, SM_OFF+1*4096,
        -1, 0.f, 0.f, 1.0f/DVf, NV, NVP, stage, Lorig, Ldst);
  };
  leval(LA_OFF, 1, LB_OFF, 0);
  leval(LB_OFF, 2, LA_OFF, LA_OFF);
  qr(LA_OFF, NVP, 4, NV, SPLIT_QRV, Q1L_OFF, NV, 0, S_OFF, SQRT_DVf, V_OFF, NV, ISQRT_DVf);

  // ---------- outputs: Xe,Se,Ve,Xi,Si,Vi ----------
  float* out = (float*)d_out;
  hipMemcpyAsync(out + 0,       W + X_OFF, FB*(size_t)R*NX, hipMemcpyDeviceToDevice, stream);
  hipMemcpyAsync(out + 1048576, W + S_OFF, FB*(size_t)R*R,  hipMemcpyDeviceToDevice, stream);
  hipMemcpyAsync(out + 1052672, W + V_OFF, FB*(size_t)R*NV, hipMemcpyDeviceToDevice, stream);
  hipMemcpyAsync(out + 1183744, W + (size_t)SPS + X_OFF, FB*(size_t)R*NX, hipMemcpyDeviceToDevice, stream);
  hipMemcpyAsync(out + 2232320, W + (size_t)SPS + S_OFF, FB*(size_t)R*R,  hipMemcpyDeviceToDevice, stream);
  hipMemcpyAsync(out + 2236416, W + (size_t)SPS + V_OFF, FB*(size_t)R*NV, hipMemcpyDeviceToDevice, stream);
  (void)in_sizes; (void)n_in; (void)out_size; (void)ws_size;
}

// Round 4
// 1931.154 us; speedup vs baseline: 4.2951x; 1.4560x over previous
//
#include <hip/hip_runtime.h>

#define R 64
#define NX 16384
#define NV 2048
#define NXP (NX+8)
#define NVP (NV+8)
#define TW 64
#define SPLIT_VM 8
#define SPLIT_X 64
#define SPLIT_QRX 32
#define SPLIT_QRV 8

#define DXf 1.220703125e-4f
#define DVf 0.0078125f
#define DTf 0.001f
#define PI_F 3.14159265358979323846f
#define FAC_E (-1.0f)
#define FAC_I (0.01f)
#define ZE_F (-1.0f)
#define ZI_F (1.0f)
#define SQRT_DXf 0.011048543456039806f
#define SQRT_DVf 0.08838834764831845f
#define ISQRT_DXf 90.50966799187808f
#define ISQRT_DVf 11.313708498984761f

// ---------------- workspace layout (float offsets), per-species stride SPS ----
#define X_OFF 0
#define V_OFF 1048576
#define S_OFF 1179648
#define S1_OFF 1183744
#define SQ_OFF 1187840
#define D_OFF 1191936
#define MATS_OFF 1196032      /* 8 mats: vplus,vminus,Vm,Vp,Vl,Vr,Vmq,Vpq */
#define SM_OFF 1228800        /* KL,KR,EpM,EmM finals */
#define R1D_OFF 1245184       /* f64 64x64 (unused now) */
#define RFD_OFF 1261568       /* f64 64x64 (unused now) */
#define R1IF_OFF 1269760      /* f32 Rinv */
#define R2IF_OFF 1273856      /* f32 (unused now) */
#define KA_OFF 1277952        /* 64 x NXP padded */
#define KB_OFF 2327040        /* 64 x NXP padded ; L-phase aliases below */
#define LA_OFF KB_OFF
#define LB_OFF (KB_OFF+131584)
#define Q1L_OFF (KB_OFF+263168)
#define VQ_OFF (KB_OFF+394240)
#define PART_OFF 3376128      /* f32 partials: 4 mats x 64 splits x 4096 */
#define PARTQR_OFF 4424704    /* f64 partials: 32 x 4096 doubles */
#define GD_OFF 4686848        /* reduced f64 gram: 4096 doubles = 8192 floats */
#define SPS 4695040
// shared region
#define RHO_OFF 9390080
#define E_OFF 9406464
#define C_OFF 9422848
#define FFT1_OFF 9426944
#define FFT2_OFF 9459712

__device__ __forceinline__ float mm2(float a, float b) {
    return (a*b > 0.0f) ? ((fabsf(a) < fabsf(b)) ? a : b) : 0.0f;
}

// ---------------- generic weighted gram: C[a][b] = sum_x av(a,x)*bv(b,x) ------
// mode 0: 6 V-matrices   mode 1: Vm/Vp masks from Vq   mode 2: K_left/K_right
// mode 3: Ep_mat/Em_mat (weight from fac*E, *DX)
__global__ __launch_bounds__(256) void k_gram(float* W, int mode, int a_off, int lda,
    int b_off, int ldb, int boff, int e_abs, float fac0, float fac1,
    int out_off, int N, int nsplit)
{
  int sp = blockIdx.z, mat = blockIdx.y, split = blockIdx.x;
  float* base = W + (size_t)sp*SPS;
  const float* A = base + a_off;
  const float* B = base + b_off;
  float fac = sp ? fac1 : fac0;
  float* outp = base + out_off + (size_t)(mat*nsplit + split)*4096;
  int chunk = N / nsplit;
  int xb0 = split * chunk;
  __shared__ float tA[TW][R+1], tB[TW][R+1];
  float acc[4][4] = {};
  int tid = threadIdx.x, ty = tid >> 4, tx = tid & 15;
  for (int xt = 0; xt < chunk; xt += TW) {
    for (int idx = tid; idx < TW*R; idx += 256) {
      int xi = idx & 63, r = idx >> 6;
      int x = xb0 + xt + xi;
      float av, bv;
      if (mode == 0) {
        float vv = A[(size_t)r*lda + x];
        float vs = ((float)x + 0.5f)*DVf - 8.0f;
        if (mat == 0)      { av = vv * (fmaxf(vs,0.f)*DVf); bv = vv; }
        else if (mat == 1) { av = vv * (fminf(vs,0.f)*DVf); bv = vv; }
        else if (mat == 2) { av = vv * ((vs<0.f)?DVf:0.f); bv = vv; }
        else if (mat == 3) { av = vv * ((vs>0.f)?DVf:0.f); bv = vv; }
        else if (mat == 4) { av = vv; bv = (x>=1)   ? (vv - A[(size_t)r*lda + x-1]) : 0.f; }
        else               { av = vv; bv = (x<NV-1) ? (A[(size_t)r*lda + x+1] - vv) : 0.f; }
      } else if (mode == 1) {
        float vv = A[(size_t)r*lda + x];
        float vs = ((float)x + 0.5f)*DVf - 8.0f;
        float w = (mat==0) ? ((vs<0.f)?DVf:0.f) : ((vs>0.f)?DVf:0.f);
        av = vv*w; bv = vv;
      } else if (mode == 2) {
        av = A[(size_t)r*lda + x];
        const float* Bp = B + (size_t)r*ldb + boff + x;
        bv = (mat==0) ? (Bp[0] - Bp[-1]) : (Bp[1] - Bp[0]);
      } else {
        float e = W[e_abs + x] * fac;
        float vv = A[(size_t)r*lda + x];
        av = vv * (((mat==0) ? fmaxf(e,0.f) : fminf(e,0.f)) * DXf);
        bv = vv;
      }
      tA[xi][r] = av; tB[xi][r] = bv;
    }
    __syncthreads();
    for (int xi = 0; xi < TW; ++xi) {
      float a0 = tA[xi][ty*4+0], a1 = tA[xi][ty*4+1], a2 = tA[xi][ty*4+2], a3 = tA[xi][ty*4+3];
      float b0 = tB[xi][tx*4+0], b1 = tB[xi][tx*4+1], b2 = tB[xi][tx*4+2], b3 = tB[xi][tx*4+3];
      acc[0][0]+=a0*b0; acc[0][1]+=a0*b1; acc[0][2]+=a0*b2; acc[0][3]+=a0*b3;
      acc[1][0]+=a1*b0; acc[1][1]+=a1*b1; acc[1][2]+=a1*b2; acc[1][3]+=a1*b3;
      acc[2][0]+=a2*b0; acc[2][1]+=a2*b1; acc[2][2]+=a2*b2; acc[2][3]+=a2*b3;
      acc[3][0]+=a3*b0; acc[3][1]+=a3*b1; acc[3][2]+=a3*b2; acc[3][3]+=a3*b3;
    }
    __syncthreads();
  }
  #pragma unroll
  for (int i = 0; i < 4; ++i)
    #pragma unroll
    for (int j = 0; j < 4; ++j)
      outp[(ty*4+i)*64 + tx*4 + j] = acc[i][j];
}

// gram with fp64 accumulation for QR (A only)
__global__ __launch_bounds__(256) void k_gram_qr(float* W, int a_off, int lda, int aoff,
    int N, int nsplit, int outd_off)
{
  int sp = blockIdx.z, split = blockIdx.x;
  float* base = W + (size_t)sp*SPS;
  const float* A = base + a_off + aoff;
  double* outp = (double*)(base + outd_off) + (size_t)split*4096;
  int chunk = N / nsplit, x0 = split*chunk;
  __shared__ float tA[TW][R+1];
  double acc[4][4] = {};
  int tid = threadIdx.x, ty = tid >> 4, tx = tid & 15;
  for (int xt = 0; xt < chunk; xt += TW) {
    for (int idx = tid; idx < TW*R; idx += 256) {
      int xi = idx & 63, r = idx >> 6;
      tA[xi][r] = A[(size_t)r*lda + x0 + xt + xi];
    }
    __syncthreads();
    for (int xi = 0; xi < TW; ++xi) {
      double a0 = tA[xi][ty*4+0], a1 = tA[xi][ty*4+1], a2 = tA[xi][ty*4+2], a3 = tA[xi][ty*4+3];
      double b0 = tA[xi][tx*4+0], b1 = tA[xi][tx*4+1], b2 = tA[xi][tx*4+2], b3 = tA[xi][tx*4+3];
      acc[0][0]+=a0*b0; acc[0][1]+=a0*b1; acc[0][2]+=a0*b2; acc[0][3]+=a0*b3;
      acc[1][0]+=a1*b0; acc[1][1]+=a1*b1; acc[1][2]+=a1*b2; acc[1][3]+=a1*b3;
      acc[2][0]+=a2*b0; acc[2][1]+=a2*b1; acc[2][2]+=a2*b2; acc[2][3]+=a2*b3;
      acc[3][0]+=a3*b0; acc[3][1]+=a3*b1; acc[3][2]+=a3*b2; acc[3][3]+=a3*b3;
    }
    __syncthreads();
  }
  #pragma unroll
  for (int i = 0; i < 4; ++i)
    #pragma unroll
    for (int j = 0; j < 4; ++j)
      outp[(ty*4+i)*64 + tx*4 + j] = acc[i][j];
}

// parallel reduce of f32 partial mats: grid (nmats, 16, 2); 256-elem slice per block
__global__ __launch_bounds__(256) void k_reduce2(float* W, int src_off, int dst_off, int nsplit)
{
  int sp = blockIdx.z, mat = blockIdx.x;
  int e = blockIdx.y*256 + threadIdx.x;
  float* base = W + (size_t)sp*SPS;
  const float* src = base + src_off + (size_t)mat*nsplit*4096 + e;
  float s = 0;
  for (int k = 0; k < nsplit; ++k) s += src[(size_t)k*4096];
  base[dst_off + (size_t)mat*4096 + e] = s;
}

// parallel reduce of f64 QR gram partials: grid (16, 1, 2); 256-elem slice per block
__global__ __launch_bounds__(256) void k_reduced(float* W, int src_off, int dst_off, int nsplit)
{
  int sp = blockIdx.z;
  int e = blockIdx.x*256 + threadIdx.x;
  float* base = W + (size_t)sp*SPS;
  const double* src = (const double*)(base + src_off) + e;
  double s = 0;
  for (int k = 0; k < nsplit; ++k) s += src[(size_t)k*4096];
  ((double*)(base + dst_off))[e] = s;
}

// C[j][x] = alpha*d[j]* sum_r coef(r,j) * B[r][x];  coef = transA? A[j][r] : A[r][j]
__global__ __launch_bounds__(256) void k_rr(float* W, int a_off, int transA, int b_off,
    int ldb, int boff, int c_off, int ldc, int coff, int d_off, float alpha)
{
  int sp = blockIdx.z;
  float* base = W + (size_t)sp*SPS;
  const float* A = base + a_off;
  const float* B = base + b_off + boff;
  float* C = base + c_off + coff;
  __shared__ float tA[R][R+1];
  __shared__ float dsc[R];
  int tid = threadIdx.x;
  for (int idx = tid; idx < R*R; idx += 256) {
    int r = idx >> 6, j = idx & 63;
    tA[r][j] = transA ? A[j*R + r] : A[idx];
  }
  if (tid < R) dsc[tid] = (d_off >= 0) ? base[d_off + tid] : 1.0f;
  __syncthreads();
  int ty = tid >> 4, tx = tid & 15;
  int x0 = blockIdx.x*64 + tx*4;
  float acc[4][4] = {};
  for (int r = 0; r < R; ++r) {
    float4 bv = *(const float4*)(B + (size_t)r*ldb + x0);
    float a0 = tA[r][ty*4+0], a1 = tA[r][ty*4+1], a2 = tA[r][ty*4+2], a3 = tA[r][ty*4+3];
    acc[0][0]+=a0*bv.x; acc[0][1]+=a0*bv.y; acc[0][2]+=a0*bv.z; acc[0][3]+=a0*bv.w;
    acc[1][0]+=a1*bv.x; acc[1][1]+=a1*bv.y; acc[1][2]+=a1*bv.z; acc[1][3]+=a1*bv.w;
    acc[2][0]+=a2*bv.x; acc[2][1]+=a2*bv.y; acc[2][2]+=a2*bv.z; acc[2][3]+=a2*bv.w;
    acc[3][0]+=a3*bv.x; acc[3][1]+=a3*bv.y; acc[3][2]+=a3*bv.z; acc[3][3]+=a3*bv.w;
  }
  #pragma unroll
  for (int i = 0; i < 4; ++i) {
    int j = ty*4 + i;
    float s = alpha * dsc[j];
    float4 o = make_float4(acc[i][0]*s, acc[i][1]*s, acc[i][2]*s, acc[i][3]*s);
    *(float4*)(C + (size_t)j*ldc + x0) = o;
  }
}

// ghosts for 2-ghost K buffer: cols 2,3 = Vm@K[:,{1,0}]; NX+4,NX+5 = Vp@K[:,{NX-1,NX-2}]
__global__ __launch_bounds__(256) void k_ghost2(float* W, int k_off)
{
  int sp = blockIdx.z;
  float* base = W + (size_t)sp*SPS;
  float* K = base + k_off;
  int tid = threadIdx.x;
  int j = tid & 63, c = tid >> 6;
  const float* M = base + MATS_OFF + ((c < 2) ? 2 : 3)*4096;
  int dst = (c==0)?2 : (c==1)?3 : (c==2)?(NX+4):(NX+5);
  int src = (c==0)?5 : (c==1)?4 : (c==2)?(NX+3):(NX+2);
  float s = 0;
  for (int m = 0; m < R; ++m) s += M[j*R + m] * K[(size_t)m*NXP + src];
  K[(size_t)j*NXP + dst] = s;
}

// ghosts for 1-ghost K buffer: col 3 = Vm@K[:,0]; NX+4 = Vp@K[:,NX-1]
__global__ __launch_bounds__(128) void k_ghost1(float* W, int k_off, int vm_idx, int vp_idx)
{
  int sp = blockIdx.z;
  float* base = W + (size_t)sp*SPS;
  float* K = base + k_off;
  int tid = threadIdx.x;
  int j = tid & 63, c = tid >> 6;
  const float* M = base + MATS_OFF + ((c==0)? vm_idx : vp_idx)*4096;
  int dst = (c==0)? 3 : (NX+4);
  int src = (c==0)? 4 : (NX+3);
  float s = 0;
  for (int m = 0; m < R; ++m) s += M[j*R + m] * K[(size_t)m*NXP + src];
  K[(size_t)j*NXP + dst] = s;
}

__global__ __launch_bounds__(256) void k_ghostL(float* W)
{
  int sp = blockIdx.z;
  float* base = W + (size_t)sp*SPS;
  for (int idx = threadIdx.x; idx < 512; idx += 256) {
    int which = idx >> 8; int r = (idx >> 2) & 63; int c = idx & 3;
    int col = (c < 2) ? (2 + c) : (NV + 4 + (c - 2));
    (base + (which ? LB_OFF : LA_OFF))[(size_t)r*NVP + col] = 0.f;
  }
}

// fused slope-limited flux divergence + extra term + SSPRK2 combine
__global__ __launch_bounds__(256) void k_flux(float* W, int U_off, int Kx_off, int ldkx,
    int kxoff, int useWin, int P_off, int Mi_off, int A2_off, int B2_off,
    int e_abs, float fac0, float fac1, float dh_inv, int N, int ldp,
    int stage, int orig_off, int out_off)
{
  int sp = blockIdx.z;
  float* base = W + (size_t)sp*SPS;
  const float* U  = base + U_off;
  const float* Kx = base + Kx_off;
  const float* Pm = base + P_off;
  const float* Mm = base + Mi_off;
  const float* Am = base + A2_off;
  const float* Bm = base + B2_off;
  float fac = sp ? fac1 : fac0;
  int x0 = blockIdx.x * 32;
  __shared__ float win[R][37];
  __shared__ float dLt[32][R+1];
  __shared__ float dRt[32][R+1];
  __shared__ float KTt[32][R+1];
  int tid = threadIdx.x;
  for (int idx = tid; idx < R*36; idx += 256) {
    int c = idx % 36, m = idx / 36;
    win[m][c] = U[(size_t)m*ldp + x0 + 2 + c];
  }
  __syncthreads();
  for (int idx = tid; idx < R*32; idx += 256) {
    int xi = idx & 31, m = idx >> 5;
    float u0 = win[m][xi], u1 = win[m][xi+1], u2 = win[m][xi+2], u3 = win[m][xi+3], u4 = win[m][xi+4];
    float d01 = u1-u0, d12 = u2-u1, d23 = u3-u2, d34 = u4-u3;
    float s1 = mm2(d01,d12), s2 = mm2(d12,d23), s3 = mm2(d23,d34);
    dLt[xi][m] = ((u2 + 0.5f*s2) - (u1 + 0.5f*s1)) * dh_inv;
    dRt[xi][m] = ((u3 - 0.5f*s3) - (u2 - 0.5f*s2)) * dh_inv;
    KTt[xi][m] = useWin ? u2 : Kx[(size_t)m*ldkx + kxoff + x0 + xi];
  }
  __syncthreads();
  int ty = tid >> 4, tx = tid & 15;
  int j0 = ty*4;
  float aP[4][2] = {}, aM[4][2] = {}, aA[4][2] = {}, aB[4][2] = {};
  for (int m = 0; m < R; ++m) {
    float dl0 = dLt[tx*2][m],   dl1 = dLt[tx*2+1][m];
    float dr0 = dRt[tx*2][m],   dr1 = dRt[tx*2+1][m];
    float kt0 = KTt[tx*2][m],   kt1 = KTt[tx*2+1][m];
    #pragma unroll
    for (int i = 0; i < 4; ++i) {
      float p = Pm[(j0+i)*R + m], q = Mm[(j0+i)*R + m];
      float a = Am[(j0+i)*R + m], b = Bm[(j0+i)*R + m];
      aP[i][0] += p*dl0; aP[i][1] += p*dl1;
      aM[i][0] += q*dr0; aM[i][1] += q*dr1;
      aA[i][0] += a*kt0; aA[i][1] += a*kt1;
      aB[i][0] += b*kt0; aB[i][1] += b*kt1;
    }
  }
  const float* orig = base + orig_off;
  float* out = base + out_off;
  for (int xx = 0; xx < 2; ++xx) {
    int x = x0 + tx*2 + xx;
    float w1, w2;
    if (e_abs >= 0) { float e = W[e_abs + x]; w1 = fac*fmaxf(e,0.f); w2 = fac*fminf(e,0.f); }
    else { float vs = ((float)x + 0.5f)*DVf - 8.0f; w1 = fmaxf(vs,0.f); w2 = fminf(vs,0.f); }
    #pragma unroll
    for (int i = 0; i < 4; ++i) {
      int j = j0 + i;
      float rhs = -(aP[i][xx] + aM[i][xx] + w1*aA[i][xx] + w2*aB[i][xx]);
      float uval = win[j][tx*2 + xx + 2];
      float res;
      if (stage == 1) res = uval + DTf*rhs;
      else res = 0.5f*(orig[(size_t)j*ldp + 4 + x] + uval + DTf*rhs);
      out[(size_t)j*ldp + 4 + x] = res;
    }
  }
}

// CholeskyQR1 tail: chol(G) -> R; blocked parallel tri-inverse -> Rinv(f32);
// T = A_top @ Rinv (fp64); LAPACK sign chain -> D; S_out = D*R*sscale.
__global__ __launch_bounds__(256) void k_cholA(float* W, int gd_off,
    int a_off, int lda, int aoff, int sout_off, float sscale)
{
  int sp = blockIdx.z;
  float* base = W + (size_t)sp*SPS;
  const double* GD = (const double*)(base + gd_off);
  const float* A = base + a_off + aoff;
  float* Rinv = base + R1IF_OFF;
  __shared__ double G[R][R+1];
  __shared__ double Wi[R][R+1];
  __shared__ double T[R][R+1];
  __shared__ float  As[R][R+1];
  __shared__ double Pb[32][33];
  __shared__ double red[4][R];
  __shared__ double dinv[R];
  __shared__ double dsh[R];
  int tid = threadIdx.x;
  int j = tid & 63, q = tid >> 6;
  for (int e = tid; e < 4096; e += 256) {
    G[e>>6][e&63] = GD[e];
    As[e>>6][e&63] = A[(size_t)(e>>6)*lda + (e&63)];
  }
  __syncthreads();
  // ---- Cholesky (upper) ----
  for (int k = 0; k < R; ++k) {
    if (q == 0) {               // wave0 lockstep: ukk loaded by all lanes before writes
      double ukk = sqrt(G[k][k]);
      if (j > k) G[k][j] /= ukk;
      else if (j == k) G[k][k] = ukk;
    }
    __syncthreads();
    if (j > k) {
      double gkj = G[k][j];
      for (int i = k+1+q; i <= j; i += 4) G[i][j] -= G[k][i]*gkj;
    }
    __syncthreads();
  }
  if (tid < R) dinv[tid] = 1.0 / G[tid][tid];
  __syncthreads();
  // ---- blocked tri-inverse: two 32x32 diagonal blocks in parallel ----
  if (q == 0) Wi[j][j] = dinv[j];
  __syncthreads();
  int blo = j & 32;   // diagonal-block base for column j
  for (int t = 1; t < 32; ++t) {
    int i = j - t;
    double s = 0;
    if (i >= blo) {
      for (int m = i+1+q; m <= j; m += 4) s += G[i][m]*Wi[m][j];
    }
    red[q][j] = s;
    __syncthreads();
    if (q == 0 && i >= blo)
      Wi[i][j] = -(red[0][j]+red[1][j]+red[2][j]+red[3][j]) * dinv[i];
    __syncthreads();
  }
  // P = R12 * W22
  for (int u = 0; u < 4; ++u) {
    int e = tid + 256*u;
    int m = e >> 5, jj = 32 + (e & 31);
    double s = 0;
    for (int k2 = 32; k2 <= jj; ++k2) s += G[m][k2]*Wi[k2][jj];
    Pb[m][jj-32] = s;
  }
  __syncthreads();
  // W12 = -W11 * P
  for (int u = 0; u < 4; ++u) {
    int e = tid + 256*u;
    int i = e >> 5, jj = 32 + (e & 31);
    double s = 0;
    for (int m = i; m < 32; ++m) s += Wi[i][m]*Pb[m][jj-32];
    Wi[i][jj] = -s;
  }
  __syncthreads();
  // Rinv f32 out (for k_rr)
  for (int e = tid; e < 4096; e += 256) {
    int i = e>>6, jj = e&63;
    Rinv[e] = (i<=jj) ? (float)Wi[i][jj] : 0.0f;
  }
  // T[x][j] = sum_m Wi[m][j] * As[m][x]   (top block of Q_pos, fp64)
  for (int x = q; x < R; x += 4) {
    double s = 0;
    for (int m = 0; m <= j; ++m) s += Wi[m][j]*(double)As[m][x];
    T[x][j] = s;
  }
  __syncthreads();
  // ---- LAPACK Householder sign chain on exact-orthonormal top block ----
  for (int k = 0; k < R; ++k) {
    double tkk = T[k][k];
    double d = (tkk >= 0.0) ? -1.0 : 1.0;
    if (tid == k) dsh[k] = d;
    if (j > k) {
      double c = d * T[k][j] / (1.0 + fabs(tkk));
      for (int m = k+1+q; m < R; m += 4) T[m][j] += c * T[m][k];
    }
    __syncthreads();
  }
  if (tid < 64) base[D_OFF + tid] = (float)dsh[tid];
  for (int e = tid; e < 4096; e += 256) {
    int i = e >> 6, jj = e & 63;
    base[sout_off + e] = (i<=jj) ? (float)(dsh[i] * G[i][jj] * (double)sscale) : 0.0f;
  }
}

// S-step small combine from pre-reduced mats at SM_OFF:
// rhs = KL@vp^T + KR@vm^T + fac*(Ep@S@Vl^T + Em@S@Vr^T)
__global__ __launch_bounds__(256) void k_sstep(float* W, int stage)
{
  int sp = blockIdx.x;
  float* base = W + (size_t)sp*SPS;
  float fac = sp ? FAC_I : FAC_E;
  __shared__ float Ab[4096], Bb[4096], Cb[4096];
  int tid = threadIdx.x, ty = tid >> 4, tx = tid & 15;
  for (int e = tid; e < 4096; e += 256) {
    Ab[e] = base[SM_OFF + e];            // KL
    Bb[e] = base[SM_OFF + 4096 + e];     // KR
  }
  __syncthreads();
  const float* vpm = base + MATS_OFF + 0*4096;
  const float* vmm = base + MATS_OFF + 1*4096;
  const float* vlm = base + MATS_OFF + 4*4096;
  const float* vrm = base + MATS_OFF + 5*4096;
  float accV[4][4] = {}, accE[4][4] = {};
  for (int m = 0; m < R; ++m) {
    float kl[4], kr[4], vpj[4], vmj[4];
    #pragma unroll
    for (int i = 0; i < 4; ++i) { kl[i] = Ab[(ty*4+i)*64+m]; kr[i] = Bb[(ty*4+i)*64+m]; }
    #pragma unroll
    for (int j = 0; j < 4; ++j) { vpj[j] = vpm[(tx*4+j)*64+m]; vmj[j] = vmm[(tx*4+j)*64+m]; }
    #pragma unroll
    for (int i = 0; i < 4; ++i)
      #pragma unroll
      for (int j = 0; j < 4; ++j)
        accV[i][j] += kl[i]*vpj[j] + kr[i]*vmj[j];
  }
  __syncthreads();
  const float* Sin = base + ((stage==1)? S_OFF : S1_OFF);
  for (int e = tid; e < 4096; e += 256) {
    Cb[e] = Sin[e];
    Ab[e] = base[SM_OFF + 2*4096 + e];   // Ep_mat
  }
  __syncthreads();
  float t1[4][4] = {};
  for (int m = 0; m < R; ++m) {
    float ar[4], cj[4];
    #pragma unroll
    for (int i = 0; i < 4; ++i) ar[i] = Ab[(ty*4+i)*64+m];
    #pragma unroll
    for (int j = 0; j < 4; ++j) cj[j] = Cb[m*64 + tx*4+j];
    #pragma unroll
    for (int i = 0; i < 4; ++i)
      #pragma unroll
      for (int j = 0; j < 4; ++j) t1[i][j] += ar[i]*cj[j];
  }
  __syncthreads();
  #pragma unroll
  for (int i = 0; i < 4; ++i)
    #pragma unroll
    for (int j = 0; j < 4; ++j) Bb[(ty*4+i)*64 + tx*4+j] = t1[i][j];
  __syncthreads();
  for (int m = 0; m < R; ++m) {
    float ar[4], vj[4];
    #pragma unroll
    for (int i = 0; i < 4; ++i) ar[i] = Bb[(ty*4+i)*64+m];
    #pragma unroll
    for (int j = 0; j < 4; ++j) vj[j] = vlm[(tx*4+j)*64+m];
    #pragma unroll
    for (int i = 0; i < 4; ++i)
      #pragma unroll
      for (int j = 0; j < 4; ++j) accE[i][j] += ar[i]*vj[j];
  }
  __syncthreads();
  for (int e = tid; e < 4096; e += 256) Ab[e] = base[SM_OFF + 3*4096 + e];  // Em_mat
  __syncthreads();
  float t2[4][4] = {};
  for (int m = 0; m < R; ++m) {
    float ar[4], cj[4];
    #pragma unroll
    for (int i = 0; i < 4; ++i) ar[i] = Ab[(ty*4+i)*64+m];
    #pragma unroll
    for (int j = 0; j < 4; ++j) cj[j] = Cb[m*64 + tx*4+j];
    #pragma unroll
    for (int i = 0; i < 4; ++i)
      #pragma unroll
      for (int j = 0; j < 4; ++j) t2[i][j] += ar[i]*cj[j];
  }
  __syncthreads();
  #pragma unroll
  for (int i = 0; i < 4; ++i)
    #pragma unroll
    for (int j = 0; j < 4; ++j) Bb[(ty*4+i)*64 + tx*4+j] = t2[i][j];
  __syncthreads();
  for (int m = 0; m < R; ++m) {
    float ar[4], vj[4];
    #pragma unroll
    for (int i = 0; i < 4; ++i) ar[i] = Bb[(ty*4+i)*64+m];
    #pragma unroll
    for (int j = 0; j < 4; ++j) vj[j] = vrm[(tx*4+j)*64+m];
    #pragma unroll
    for (int i = 0; i < 4; ++i)
      #pragma unroll
      for (int j = 0; j < 4; ++j) accE[i][j] += ar[i]*vj[j];
  }
  #pragma unroll
  for (int i = 0; i < 4; ++i)
    #pragma unroll
    for (int j = 0; j < 4; ++j) {
      int e = (ty*4+i)*64 + tx*4+j;
      float rhs = accV[i][j] + fac*accE[i][j];
      if (stage == 1) base[S1_OFF + e] = base[S_OFF + e] + DTf*rhs;
      else base[S_OFF + e] = 0.5f*(base[S_OFF + e] + base[S1_OFF + e] + DTf*rhs);
    }
}

// charge moments: c = Z * S @ (V @ 1 * DV)
__global__ __launch_bounds__(256) void k_csolve(float* W)
{
  int sp = blockIdx.x;
  float* base = W + (size_t)sp*SPS;
  const float* V = base + V_OFF;
  const float* S = base + S_OFF;
  __shared__ float red[R][4];
  __shared__ float mass[R];
  int tid = threadIdx.x;
  int r = tid >> 2, q = tid & 3;
  float s = 0;
  for (int v = q; v < NV; v += 4) s += V[(size_t)r*NV + v];
  red[r][q] = s;
  __syncthreads();
  if (tid < R) mass[tid] = (red[tid][0]+red[tid][1]+red[tid][2]+red[tid][3]) * DVf;
  __syncthreads();
  if (tid < R) {
    float c = 0;
    for (int j = 0; j < R; ++j) c += S[tid*R + j] * mass[j];
    W[C_OFF + sp*R + tid] = c * (sp ? ZI_F : ZE_F);
  }
}

__global__ __launch_bounds__(256) void k_rho(float* W)
{
  int x = blockIdx.x*256 + threadIdx.x;
  float s = 0;
  for (int r = 0; r < R; ++r) s += W[X_OFF + (size_t)r*NX + x] * W[C_OFF + r];
  for (int r = 0; r < R; ++r) s += W[(size_t)SPS + X_OFF + (size_t)r*NX + x] * W[C_OFF + R + r];
  W[RHO_OFF + x] = s;
}

// -------- FFT: length-128 radix-2 DIT in LDS, 64 threads --------
__device__ inline void fft128fwd(float2* b, int t)
{
  __syncthreads();
  int r0 = (int)(__brev((unsigned)t) >> 25);
  int r1 = (int)(__brev((unsigned)(t+64)) >> 25);
  float2 a0 = b[r0], a1 = b[r1];
  __syncthreads();
  b[t] = a0; b[t+64] = a1;
  for (int s = 1; s <= 7; ++s) {
    __syncthreads();
    int half = 1 << (s-1);
    int jj = t & (half-1);
    int g  = t >> (s-1);
    int pos = (g << s) + jj;
    float ang = -2.0f*PI_F*(float)jj / (float)(1 << s);
    float sn, cs; sincosf(ang, &sn, &cs);
    float2 u = b[pos], wv = b[pos+half];
    float2 v = make_float2(wv.x*cs - wv.y*sn, wv.x*sn + wv.y*cs);
    b[pos] = make_float2(u.x+v.x, u.y+v.y);
    b[pos+half] = make_float2(u.x-v.x, u.y-v.y);
  }
}

// pass A: per-n1 length-128 FFT over n2 (stride 128) + four-step twiddle, write transposed
__global__ __launch_bounds__(64) void k_fftA(float* W, int rin_off, int cin_off, int out_off)
{
  __shared__ float2 bb[128];
  int n1 = blockIdx.x, t = threadIdx.x;
  if (rin_off >= 0) {
    const float* rin = W + rin_off;
    bb[t]    = make_float2(rin[n1 + 128*t], 0.f);
    bb[t+64] = make_float2(rin[n1 + 128*(t+64)], 0.f);
  } else {
    const float2* cin = (const float2*)(W + cin_off);
    bb[t] = cin[n1 + 128*t]; bb[t+64] = cin[n1 + 128*(t+64)];
  }
  fft128fwd(bb, t);
  __syncthreads();
  float2* outp = (float2*)(W + out_off);
  for (int kk = 0; kk < 2; ++kk) {
    int k2 = t + 64*kk;
    float ang = -2.0f*PI_F*(float)(n1*k2) * (1.0f/16384.0f);
    float sn, cs; sincosf(ang, &sn, &cs);
    float2 v = bb[k2];
    outp[k2*128 + n1] = make_float2(v.x*cs - v.y*sn, v.x*sn + v.y*cs);
  }
}

// pass B: per-k2 FFT over n1; spectral scale 1/(ik); write conj(H) in natural order
__global__ __launch_bounds__(64) void k_fftB(float* W, int in_off, int out_off)
{
  __shared__ float2 bb[128];
  int k2 = blockIdx.x, t = threadIdx.x;
  const float2* in = (const float2*)(W + in_off);
  bb[t] = in[k2*128 + t]; bb[t+64] = in[k2*128 + t + 64];
  fft128fwd(bb, t);
  __syncthreads();
  float2* outp = (float2*)(W + out_off);
  for (int kk = 0; kk < 2; ++kk) {
    int k1 = t + 64*kk;
    int j = k2 + 128*k1;
    float2 X = bb[k1];
    float2 Hc;
    if (j == 0) Hc = make_float2(0.f, 0.f);
    else {
      float kphys = PI_F * (float)((j < 8192) ? j : (j - 16384));
      Hc = make_float2(X.y / kphys, X.x / kphys);   // conj(rho_hat/(i k))
    }
    outp[j] = Hc;
  }
}

// pass D: final FFT pass, take Re()/N -> E
__global__ __launch_bounds__(64) void k_fftD(float* W, int in_off, int e_off)
{
  __shared__ float2 bb[128];
  int k2 = blockIdx.x, t = threadIdx.x;
  const float2* in = (const float2*)(W + in_off);
  bb[t] = in[k2*128 + t]; bb[t+64] = in[k2*128 + t + 64];
  fft128fwd(bb, t);
  __syncthreads();
  for (int kk = 0; kk < 2; ++kk) {
    int k1 = t + 64*kk;
    W[e_off + k2 + 128*k1] = bb[k1].x * (1.0f/16384.0f);
  }
}

// ----------------------------------------------------------------------------
extern "C" void kernel_launch(void* const* d_in, const int* in_sizes, int n_in,
                              void* d_out, int out_size, void* d_ws, size_t ws_size,
                              hipStream_t stream)
{
  float* W = (float*)d_ws;
  const size_t FB = sizeof(float);
  // inputs: Xe, Se, Ve, Xi, Si, Vi
  hipMemcpyAsync(W + X_OFF, d_in[0], FB*(size_t)R*NX, hipMemcpyDeviceToDevice, stream);
  hipMemcpyAsync(W + S_OFF, d_in[1], FB*(size_t)R*R,  hipMemcpyDeviceToDevice, stream);
  hipMemcpyAsync(W + V_OFF, d_in[2], FB*(size_t)R*NV, hipMemcpyDeviceToDevice, stream);
  hipMemcpyAsync(W + (size_t)SPS + X_OFF, d_in[3], FB*(size_t)R*NX, hipMemcpyDeviceToDevice, stream);
  hipMemcpyAsync(W + (size_t)SPS + S_OFF, d_in[4], FB*(size_t)R*R,  hipMemcpyDeviceToDevice, stream);
  hipMemcpyAsync(W + (size_t)SPS + V_OFF, d_in[5], FB*(size_t)R*NV, hipMemcpyDeviceToDevice, stream);

  // V-derived matrices (vplus,vminus,Vm,Vp,Vl,Vr)
  k_gram<<<dim3(SPLIT_VM,6,2),256,0,stream>>>(W, 0, V_OFF, NV, V_OFF, NV, 0, -1, 0.f,0.f, PART_OFF, NV, SPLIT_VM);
  k_reduce2<<<dim3(6,16,2),256,0,stream>>>(W, PART_OFF, MATS_OFF, SPLIT_VM);

  auto poisson = [&]() {
    k_csolve<<<dim3(2),256,0,stream>>>(W);
    k_rho<<<dim3(NX/256),256,0,stream>>>(W);
    k_fftA<<<dim3(128),64,0,stream>>>(W, RHO_OFF, -1, FFT1_OFF);
    k_fftB<<<dim3(128),64,0,stream>>>(W, FFT1_OFF, FFT2_OFF);
    k_fftA<<<dim3(128),64,0,stream>>>(W, -1, FFT2_OFF, FFT1_OFF);
    k_fftD<<<dim3(128),64,0,stream>>>(W, FFT1_OFF, E_OFF);
  };

  // CholeskyQR1 + LAPACK-sign emulation
  auto qr = [&](int a_off, int lda, int aoff, int N_, int nsplit,
                int sout_off, float sscale, int xout_off, int xout_ld, float inv_s) {
    k_gram_qr<<<dim3(nsplit,1,2),256,0,stream>>>(W, a_off, lda, aoff, N_, nsplit, PARTQR_OFF);
    k_reduced<<<dim3(16,1,2),256,0,stream>>>(W, PARTQR_OFF, GD_OFF, nsplit);
    k_cholA<<<dim3(1,1,2),256,0,stream>>>(W, GD_OFF, a_off, lda, aoff, sout_off, sscale);
    k_rr<<<dim3(N_/64,1,2),256,0,stream>>>(W, R1IF_OFF, 0, a_off, lda, aoff, xout_off, xout_ld, 0, D_OFF, inv_s);
  };

  // ---------- Poisson #1 + K-step ----------
  poisson();
  k_rr<<<dim3(NX/64,1,2),256,0,stream>>>(W, S_OFF, 0, X_OFF, NX, 0, KA_OFF, NXP, 4, -1, 1.0f);
  k_ghost2<<<dim3(1,1,2),256,0,stream>>>(W, KA_OFF);
  k_flux<<<dim3(NX/32,1,2),256,0,stream>>>(W, KA_OFF, KA_OFF, NXP, 4, 1,
      MATS_OFF+0*4096, MATS_OFF+1*4096, MATS_OFF+4*4096, MATS_OFF+5*4096,
      E_OFF, FAC_E, FAC_I, 1.0f/DXf, NX, NXP, 1, 0, KB_OFF);
  k_ghost2<<<dim3(1,1,2),256,0,stream>>>(W, KB_OFF);
  k_flux<<<dim3(NX/32,1,2),256,0,stream>>>(W, KB_OFF, KB_OFF, NXP, 4, 1,
      MATS_OFF+0*4096, MATS_OFF+1*4096, MATS_OFF+4*4096, MATS_OFF+5*4096,
      E_OFF, FAC_E, FAC_I, 1.0f/DXf, NX, NXP, 2, KA_OFF, KA_OFF);
  qr(KA_OFF, NXP, 4, NX, SPLIT_QRX, S_OFF, SQRT_DXf, X_OFF, NX, ISQRT_DXf);

  // ---------- Poisson #2 + S-step ----------
  poisson();
  auto sstep_eval = [&](int stage) {
    int sin = (stage==1) ? S_OFF : S1_OFF;
    k_rr<<<dim3(NX/64,1,2),256,0,stream>>>(W, sin, 0, X_OFF, NX, 0, KA_OFF, NXP, 4, -1, 1.0f);
    k_ghost1<<<dim3(1,1,2),128,0,stream>>>(W, KA_OFF, 2, 3);
    k_gram<<<dim3(SPLIT_X,2,2),256,0,stream>>>(W, 2, X_OFF, NX, KA_OFF, NXP, 4, -1, 0.f,0.f, PART_OFF, NX, SPLIT_X);
    k_gram<<<dim3(SPLIT_X,2,2),256,0,stream>>>(W, 3, X_OFF, NX, 0, 0, 0, E_OFF, 1.0f, 1.0f, PART_OFF + 2*SPLIT_X*4096, NX, SPLIT_X);
    k_reduce2<<<dim3(4,16,2),256,0,stream>>>(W, PART_OFF, SM_OFF, SPLIT_X);
    k_sstep<<<dim3(2),256,0,stream>>>(W, stage);
  };
  sstep_eval(1);
  sstep_eval(2);

  // ---------- Poisson #3 + L-step ----------
  poisson();
  k_rr<<<dim3(NV/64,1,2),256,0,stream>>>(W, S_OFF, 1, V_OFF, NV, 0, LA_OFF, NVP, 4, -1, 1.0f);
  k_ghostL<<<dim3(1,1,2),256,0,stream>>>(W);
  auto leval = [&](int Lsrc, int stage, int Ldst, int Lorig) {
    qr(Lsrc, NVP, 4, NV, SPLIT_QRV, SQ_OFF, SQRT_DVf, VQ_OFF, NV, ISQRT_DVf);
    k_gram<<<dim3(SPLIT_VM,2,2),256,0,stream>>>(W, 1, VQ_OFF, NV, VQ_OFF, NV, 0, -1, 0.f,0.f, PART_OFF, NV, SPLIT_VM);
    k_reduce2<<<dim3(2,16,2),256,0,stream>>>(W, PART_OFF, MATS_OFF + 6*4096, SPLIT_VM);
    k_rr<<<dim3(NX/64,1,2),256,0,stream>>>(W, SQ_OFF, 0, X_OFF, NX, 0, KA_OFF, NXP, 4, -1, 1.0f);
    k_ghost1<<<dim3(1,1,2),128,0,stream>>>(W, KA_OFF, 6, 7);
    k_gram<<<dim3(SPLIT_X,2,2),256,0,stream>>>(W, 2, X_OFF, NX, KA_OFF, NXP, 4, -1, 0.f,0.f, PART_OFF, NX, SPLIT_X);
    k_gram<<<dim3(SPLIT_X,2,2),256,0,stream>>>(W, 3, X_OFF, NX, 0, 0, 0, E_OFF, FAC_E, FAC_I, PART_OFF + 2*SPLIT_X*4096, NX, SPLIT_X);
    k_reduce2<<<dim3(4,16,2),256,0,stream>>>(W, PART_OFF, SM_OFF, SPLIT_X);
    k_flux<<<dim3(NV/32,1,2),256,0,stream>>>(W, Lsrc, VQ_OFF, NV, 0, 0,
        SM_OFF+2*4096, SM_OFF+3*4096, SM_OFF+0*4096, SM_OFF+1*4096,
        -1, 0.f, 0.f, 1.0f/DVf, NV, NVP, stage, Lorig, Ldst);
  };
  leval(LA_OFF, 1, LB_OFF, 0);
  leval(LB_OFF, 2, LA_OFF, LA_OFF);
  qr(LA_OFF, NVP, 4, NV, SPLIT_QRV, S_OFF, SQRT_DVf, V_OFF, NV, ISQRT_DVf);

  // ---------- outputs: Xe,Se,Ve,Xi,Si,Vi ----------
  float* out = (float*)d_out;
  hipMemcpyAsync(out + 0,       W + X_OFF, FB*(size_t)R*NX, hipMemcpyDeviceToDevice, stream);
  hipMemcpyAsync(out + 1048576, W + S_OFF, FB*(size_t)R*R,  hipMemcpyDeviceToDevice, stream);
  hipMemcpyAsync(out + 1052672, W + V_OFF, FB*(size_t)R*NV, hipMemcpyDeviceToDevice, stream);
  hipMemcpyAsync(out + 1183744, W + (size_t)SPS + X_OFF, FB*(size_t)R*NX, hipMemcpyDeviceToDevice, stream);
  hipMemcpyAsync(out + 2232320, W + (size_t)SPS + S_OFF, FB*(size_t)R*R,  hipMemcpyDeviceToDevice, stream);
  hipMemcpyAsync(out + 2236416, W + (size_t)SPS + V_OFF, FB*(size_t)R*NV, hipMemcpyDeviceToDevice, stream);
  (void)in_sizes; (void)n_in; (void)out_size; (void)ws_size;
}